// Round 1
// 321.979 us; speedup vs baseline: 1.0028x; 1.0028x over previous
//
#include <hip/hip_runtime.h>
#include <hip/hip_bf16.h>
#include <hip/hip_fp16.h>

// Performer (FAVOR+) attention forward — all-MFMA pipeline, v4.
// B=2, N=4096, H=16, D=64, M=266 (padded 288), DIM=1024.
// R8: qdashout LDS cut 77KB->39KB (proj/qp buffer merged, ctxT restage
//     dropped -> PV B-frags read from global/L2); proj LDS tiles XOR-
//     swizzled (16B-block kb^(m&7)) in qdashout/kmax/kctx to kill the
//     stride-128B same-bank conflict.

#define B_   2
#define N_   4096
#define H_   16
#define M_   266
#define MP_  288     // M padded to 18*16
#define DIM_ 1024
#define RT_  8192    // B_*N_
#define BH_  32      // B_*H_
#define LKN  40      // kctx LDS stride (n-dim 32 padded)
#define LSB  296     // qp LDS row stride (288 + 8)
#define NCH  16      // kctx n-chunks per bh

typedef __attribute__((ext_vector_type(8))) short s8v;   // 8 x bf16
typedef __attribute__((ext_vector_type(4))) float f4v;   // MFMA acc

__device__ __forceinline__ ushort f2bu(float x){ __hip_bfloat16 h = __float2bfloat16(x); return *(ushort*)&h; }

constexpr float NORMC  = 0.35355339059327379f;  // 64^-0.25
constexpr float RATIOC = 0.06131393f;           // 266^-0.5
constexpr float DIAGC  = 0.0625f;               // 0.5 * 64^-0.5
constexpr float EPSC   = 1e-4f;

__device__ __forceinline__ unsigned encf(float x){
    unsigned b = __float_as_uint(x);
    return (b & 0x80000000u) ? ~b : (b | 0x80000000u);
}
__device__ __forceinline__ float decf(unsigned u){
    unsigned b = (u & 0x80000000u) ? (u ^ 0x80000000u) : ~u;
    return __uint_as_float(b);
}

__device__ __forceinline__ void stf(float* p, float v){ *p = v; }
__device__ __forceinline__ void stf(__hip_bfloat16* p, float v){ *p = __float2bfloat16(v); }

// async global->LDS, 16B per lane; lds dest wave-uniform base (+lane*16 by HW)
__device__ __forceinline__ void gl_lds16(const ushort* g, ushort* l){
    __builtin_amdgcn_global_load_lds(
        (const __attribute__((address_space(1))) unsigned int*)(const unsigned int*)g,
        (__attribute__((address_space(3))) unsigned int*)(unsigned int*)l,
        16, 0, 0);
}

// ---------------------------------------------------------------------------
// Casts
// ---------------------------------------------------------------------------
__global__ void cast_x(const float* __restrict__ s, ushort* __restrict__ d){
    const int i = (blockIdx.x * 256 + threadIdx.x) * 8;
    const float4 a = *(const float4*)&s[i];
    const float4 b = *(const float4*)&s[i + 4];
    ushort4 lo, hi;
    lo.x = f2bu(a.x); lo.y = f2bu(a.y); lo.z = f2bu(a.z); lo.w = f2bu(a.w);
    hi.x = f2bu(b.x); hi.y = f2bu(b.y); hi.z = f2bu(b.z); hi.w = f2bu(b.w);
    *(ushort4*)&d[i]     = lo;
    *(ushort4*)&d[i + 4] = hi;
}

__global__ void cast_w(const float* s0, const float* s1, const float* s2, const float* s3,
                       ushort* d0, ushort* d1, ushort* d2, ushort* d3){
    const float* s; ushort* d;
    switch (blockIdx.y) {
        case 0: s = s0; d = d0; break;
        case 1: s = s1; d = d1; break;
        case 2: s = s2; d = d2; break;
        default: s = s3; d = d3; break;
    }
    const int i = (blockIdx.x * 256 + threadIdx.x) * 8;
    const float4 a = *(const float4*)&s[i];
    const float4 b = *(const float4*)&s[i + 4];
    ushort4 lo, hi;
    lo.x = f2bu(a.x); lo.y = f2bu(a.y); lo.z = f2bu(a.z); lo.w = f2bu(a.w);
    hi.x = f2bu(b.x); hi.y = f2bu(b.y); hi.z = f2bu(b.z); hi.w = f2bu(b.w);
    *(ushort4*)&d[i]     = lo;
    *(ushort4*)&d[i + 4] = hi;
}

__global__ void cast_proj(const float* __restrict__ p, ushort* __restrict__ pb){
    const int i = blockIdx.x * 256 + threadIdx.x;
    if (i >= MP_ * 64) return;
    const int m = i >> 6, dc = i & 63;
    pb[i] = f2bu((m < M_) ? NORMC * p[m * 64 + dc] : 0.f);
}

// ---------------------------------------------------------------------------
// 128x128 MFMA GEMM with global_load_lds staging (m97 structure).
// ---------------------------------------------------------------------------
template<bool DIAG, bool BIAS, typename TC>
__launch_bounds__(256)
__global__ void gemm128(const ushort* __restrict__ A, const ushort* __restrict__ Bw,
                        const float* __restrict__ bias, TC* __restrict__ C,
                        float* __restrict__ diag)
{
    __shared__ ushort As[128 * 32];
    __shared__ ushort Bs[128 * 32];

    const int tid  = threadIdx.x;
    const int lane = tid & 63, wave = tid >> 6;
    const int col  = lane & 15, quad = lane >> 4;
    const int wm   = (wave & 1) * 64, wn = (wave >> 1) * 64;
    const int r0   = blockIdx.y * 128, c0 = blockIdx.x * 128;

    const int f0 = tid * 8;                       // flat elem offset (16B/lane)
    const int row0 = f0 >> 5, kc0 = f0 & 31;
    const size_t aoff0 = (size_t)(r0 + row0) * DIM_ + kc0;
    const size_t aoff1 = (size_t)(r0 + 64 + row0) * DIM_ + kc0;
    const size_t boff0 = (size_t)(c0 + row0) * DIM_ + kc0;
    const size_t boff1 = (size_t)(c0 + 64 + row0) * DIM_ + kc0;
    ushort* asb0 = &As[wave * 512];        // wave-uniform LDS bases
    ushort* asb1 = &As[2048 + wave * 512];
    ushort* bsb0 = &Bs[wave * 512];
    ushort* bsb1 = &Bs[2048 + wave * 512];

    f4v acc[4][4];
    #pragma unroll
    for (int i = 0; i < 4; ++i)
        #pragma unroll
        for (int j = 0; j < 4; ++j) acc[i][j] = (f4v){0.f, 0.f, 0.f, 0.f};

    for (int kk = 0; kk < DIM_; kk += 32) {
        gl_lds16(&A[aoff0 + kk],  asb0);
        gl_lds16(&A[aoff1 + kk],  asb1);
        gl_lds16(&Bw[boff0 + kk], bsb0);
        gl_lds16(&Bw[boff1 + kk], bsb1);
        __syncthreads();
        s8v af[4], bf[4];
        #pragma unroll
        for (int i = 0; i < 4; ++i)
            af[i] = *(const s8v*)&As[(wm + i * 16 + col) * 32 + quad * 8];
        #pragma unroll
        for (int j = 0; j < 4; ++j)
            bf[j] = *(const s8v*)&Bs[(wn + j * 16 + col) * 32 + quad * 8];
        #pragma unroll
        for (int i = 0; i < 4; ++i)
            #pragma unroll
            for (int j = 0; j < 4; ++j)
                acc[i][j] = __builtin_amdgcn_mfma_f32_16x16x32_bf16(af[i], bf[j], acc[i][j], 0, 0, 0);
        __syncthreads();
    }

    float bb[4] = {0.f, 0.f, 0.f, 0.f};
    if (BIAS) {
        #pragma unroll
        for (int j = 0; j < 4; ++j) bb[j] = bias[c0 + wn + j * 16 + col];
    }
    #pragma unroll
    for (int i = 0; i < 4; ++i) {
        #pragma unroll
        for (int r = 0; r < 4; ++r) {
            const size_t grow = (size_t)(r0 + wm + i * 16 + quad * 4 + r);
            #pragma unroll
            for (int j = 0; j < 4; ++j)
                stf(&C[grow * DIM_ + c0 + wn + j * 16 + col], acc[i][j][r] + bb[j]);
        }
    }
    if (DIAG) {
        const int hglob = (c0 + wn) >> 6;
        #pragma unroll
        for (int i = 0; i < 4; ++i) {
            #pragma unroll
            for (int r = 0; r < 4; ++r) {
                float s = 0.f;
                #pragma unroll
                for (int j = 0; j < 4; ++j) s += acc[i][j][r] * acc[i][j][r];
                s += __shfl_xor(s, 1); s += __shfl_xor(s, 2);
                s += __shfl_xor(s, 4); s += __shfl_xor(s, 8);
                if (col == 0)
                    diag[(size_t)(r0 + wm + i * 16 + quad * 4 + r) * H_ + hglob] = DIAGC * s;
            }
        }
    }
}

// ---------------------------------------------------------------------------
// Pass 1: global max over (n,m) of kdash per bh. No stores. Grid (16, 32).
// proj LDS tile XOR-swizzled: 16B block kb stored at kb^(m&7).
// ---------------------------------------------------------------------------
__launch_bounds__(256)
__global__ void kmax_mfma(const ushort* __restrict__ Kb, const ushort* __restrict__ projb,
                          unsigned* __restrict__ kmaxb)
{
    __shared__ ushort Pl[MP_ * 64];   // 36864 B
    __shared__ float wmx[4];
    const int tid  = threadIdx.x;
    const int lane = tid & 63, wave = tid >> 6;
    const int col  = lane & 15, quad = lane >> 4;
    const int bh   = blockIdx.y, b = bh >> 4, h = bh & 15;

    for (int i = tid; i < MP_ * 8; i += 256) {
        const int m = i >> 3, c = i & 7;
        *(uint4*)&Pl[m * 64 + ((c ^ (m & 7)) << 3)] = *(const uint4*)&projb[m * 64 + (c << 3)];
    }
    __syncthreads();

    const int sw0 = (quad ^ (col & 7)) << 3;          // m&7 == col&7 (rows t*16+col)
    const int sw1 = ((quad | 4) ^ (col & 7)) << 3;

    float mx = -3.4e38f;
    for (int ni = 0; ni < 4; ++ni) {
        const int nb = blockIdx.x * 256 + ni * 64;
        const size_t arow = ((size_t)(b * N_ + nb + wave * 16 + col)) * DIM_ + h * 64 + quad * 8;
        const s8v af0 = *(const s8v*)&Kb[arow];
        const s8v af1 = *(const s8v*)&Kb[arow + 32];
        #pragma unroll
        for (int t = 0; t < 17; ++t) {
            const s8v bf0 = *(const s8v*)&Pl[(t * 16 + col) * 64 + sw0];
            const s8v bf1 = *(const s8v*)&Pl[(t * 16 + col) * 64 + sw1];
            f4v a = (f4v){0.f, 0.f, 0.f, 0.f};
            a = __builtin_amdgcn_mfma_f32_16x16x32_bf16(af0, bf0, a, 0, 0, 0);
            a = __builtin_amdgcn_mfma_f32_16x16x32_bf16(af1, bf1, a, 0, 0, 0);
            if (t * 16 + col < M_) {
                #pragma unroll
                for (int r = 0; r < 4; ++r) mx = fmaxf(mx, a[r]);
            }
        }
    }
    #pragma unroll
    for (int o = 32; o > 0; o >>= 1) mx = fmaxf(mx, __shfl_xor(mx, o));
    if (lane == 0) wmx[wave] = mx;
    __syncthreads();
    if (tid == 0)
        atomicMax(&kmaxb[bh], encf(fmaxf(fmaxf(wmx[0], wmx[1]), fmaxf(wmx[2], wmx[3]))));
}

// ---------------------------------------------------------------------------
// Pass 2: partial ctx/kcs per n-chunk, NO atomics. Grid (NCH, 32).
// ctxp[bh][chunk][m][e] (fp32), kcsp[bh][chunk][m]. proj swizzled as above.
// ---------------------------------------------------------------------------
__launch_bounds__(256)
__global__ void kctx_mfma(const ushort* __restrict__ Kb, const ushort* __restrict__ Vb,
                          const ushort* __restrict__ projb,
                          const float* __restrict__ diagK, const unsigned* __restrict__ kmaxb,
                          float* __restrict__ ctxp, float* __restrict__ kcsp)
{
    __shared__ ushort Pl[MP_ * 64];    // 36864 B (proj, resident, swizzled)
    __shared__ ushort Kp[MP_ * LKN];   // 23040 B (kp^T tile [m][n32])
    __shared__ ushort Vt[64 * LKN];    //  5120 B (V^T tile [e][n32])
    __shared__ float kred[2][MP_];     //  2304 B

    const int tid  = threadIdx.x;
    const int lane = tid & 63, wave = tid >> 6;
    const int col  = lane & 15, quad = lane >> 4;
    const int bh   = blockIdx.y, b = bh >> 4, h = bh & 15;
    const int n0   = blockIdx.x * (N_ / NCH);
    const float kmax = decf(kmaxb[bh]);
    const int rowblk = wave >> 1;            // waves 0,1 -> n-rows 0-15; 2,3 -> 16-31
    const int t0 = (wave & 1) * 9;           // m-tiles: 0..8 / 9..17 (covers all 18)
    const int t1 = t0 + 9;

    for (int i = tid; i < MP_ * 8; i += 256) {
        const int m = i >> 3, c = i & 7;
        *(uint4*)&Pl[m * 64 + ((c ^ (m & 7)) << 3)] = *(const uint4*)&projb[m * 64 + (c << 3)];
    }
    const int sw0 = (quad ^ (col & 7)) << 3;
    const int sw1 = ((quad | 4) ^ (col & 7)) << 3;

    f4v facc[18];
    #pragma unroll
    for (int t = 0; t < 18; ++t) facc[t] = (f4v){0.f, 0.f, 0.f, 0.f};
    float kcsa[9] = {};

    __syncthreads();

    for (int ks = 0; ks < (N_ / NCH) / 32; ++ks) {
        const int nb = n0 + ks * 32;
        // V^T stage: thread handles n = tid&31, e = (tid>>5)*8 .. +7
        {
            const int n = tid & 31, e0 = (tid >> 5) * 8;
            const s8v vv = *(const s8v*)&Vb[((size_t)(b * N_ + nb + n)) * DIM_ + h * 64 + e0];
            #pragma unroll
            for (int j = 0; j < 8; ++j) Vt[(e0 + j) * LKN + n] = ((const ushort*)&vv)[j];
        }
        // dd via MFMA: A-rows = K rows nb + rowblk*16 + col
        const size_t arow = ((size_t)(b * N_ + nb + rowblk * 16 + col)) * DIM_ + h * 64 + quad * 8;
        const s8v af0 = *(const s8v*)&Kb[arow];
        const s8v af1 = *(const s8v*)&Kb[arow + 32];
        float dgr[4];
        #pragma unroll
        for (int r = 0; r < 4; ++r)
            dgr[r] = diagK[((size_t)(b * N_ + nb + rowblk * 16 + quad * 4 + r)) * H_ + h];
        for (int t = t0; t < t1; ++t) {
            const s8v bf0 = *(const s8v*)&Pl[(t * 16 + col) * 64 + sw0];
            const s8v bf1 = *(const s8v*)&Pl[(t * 16 + col) * 64 + sw1];
            f4v a = (f4v){0.f, 0.f, 0.f, 0.f};
            a = __builtin_amdgcn_mfma_f32_16x16x32_bf16(af0, bf0, a, 0, 0, 0);
            a = __builtin_amdgcn_mfma_f32_16x16x32_bf16(af1, bf1, a, 0, 0, 0);
            const int m = t * 16 + col;
            float kp[4];
            #pragma unroll
            for (int r = 0; r < 4; ++r) {
                float v = 0.f;
                if (m < M_) v = RATIOC * (__expf(a[r] - dgr[r] - kmax) + EPSC);
                kp[r] = v;
            }
            kcsa[t - t0] += kp[0] + kp[1] + kp[2] + kp[3];
            ushort4 pk;
            pk.x = f2bu(kp[0]); pk.y = f2bu(kp[1]); pk.z = f2bu(kp[2]); pk.w = f2bu(kp[3]);
            *(ushort4*)&Kp[m * LKN + rowblk * 16 + quad * 4] = pk;   // 4 consecutive n
        }
        __syncthreads();
        // out: wave owns e-tile = wave*16, all 18 m-tiles, k = 32 (this chunk)
        const s8v bfe = *(const s8v*)&Vt[(wave * 16 + col) * LKN + quad * 8];
        #pragma unroll
        for (int t = 0; t < 18; ++t) {
            const s8v am = *(const s8v*)&Kp[(t * 16 + col) * LKN + quad * 8];
            facc[t] = __builtin_amdgcn_mfma_f32_16x16x32_bf16(am, bfe, facc[t], 0, 0, 0);
        }
        __syncthreads();
    }

    // partial ctx: plain stores (D layout: m = t*16+quad*4+r, e = wave*16+col)
    const size_t pbase = ((size_t)bh * NCH + blockIdx.x) * (MP_ * 64);
    #pragma unroll
    for (int t = 0; t < 18; ++t) {
        #pragma unroll
        for (int r = 0; r < 4; ++r)
            ctxp[pbase + (size_t)(t * 16 + quad * 4 + r) * 64 + wave * 16 + col] = facc[t][r];
    }
    // partial kcs via LDS combine (waves 0/1 -> kred[0], 2/3 -> kred[1])
    for (int t = t0; t < t1; ++t) {
        float s = kcsa[t - t0];
        s += __shfl_xor(s, 16);
        s += __shfl_xor(s, 32);
        if (quad == 0) kred[rowblk][t * 16 + col] = s;
    }
    __syncthreads();
    for (int i = tid; i < MP_; i += 256)
        kcsp[((size_t)bh * NCH + blockIdx.x) * MP_ + i] = kred[0][i] + kred[1][i];
}

// ---------------------------------------------------------------------------
// Reduce partials: ctxT[bh][e][m] (bf16) + kcs[bh][m]. Grid (8, 32).
// ---------------------------------------------------------------------------
__launch_bounds__(256)
__global__ void ctx_reduce(const float* __restrict__ ctxp, const float* __restrict__ kcsp,
                           ushort* __restrict__ ctxT, float* __restrict__ kcs)
{
    const int bh = blockIdx.y, tid = threadIdx.x;
    const int base = blockIdx.x * (MP_ * 64 / 8);   // 2304
    const size_t cb = (size_t)bh * NCH * (MP_ * 64);
    #pragma unroll
    for (int u = 0; u < 9; ++u) {
        const int flat = base + u * 256 + tid;
        float s = 0.f;
        #pragma unroll
        for (int c = 0; c < NCH; ++c) s += ctxp[cb + (size_t)c * (MP_ * 64) + flat];
        const int m = flat >> 6, e = flat & 63;
        ctxT[((size_t)bh * 64 + e) * MP_ + m] = f2bu(s);
    }
    if (blockIdx.x == 0) {
        for (int i = tid; i < MP_; i += 256) {
            float s = 0.f;
            #pragma unroll
            for (int c = 0; c < NCH; ++c) s += kcsp[((size_t)bh * NCH + c) * MP_ + i];
            kcs[(size_t)bh * MP_ + i] = s;
        }
    }
}

// ---------------------------------------------------------------------------
// Fused Q path, v4: ONE shared buffer SB reused (proj swizzled -> qp tile),
// PV B-fragments read straight from global ctxT (36 KB/bh, L2-resident,
// shared by 64 blocks). LDS 77KB -> 39KB => 4 workgroups/CU. Grid (64, 32).
// ---------------------------------------------------------------------------
__launch_bounds__(256)
__global__ void qdashout(const ushort* __restrict__ Qb, const ushort* __restrict__ projb,
                         const float* __restrict__ diagQ, const float* __restrict__ kcs,
                         const ushort* __restrict__ ctxT, ushort* __restrict__ Ab)
{
    __shared__ ushort SB[64 * LSB];   // 37888 B: proj swizzled [m][64] (18432) then qp [n][LSB]
    __shared__ float kcl[MP_];
    __shared__ float dinv[64];

    const int tid  = threadIdx.x;
    const int lane = tid & 63, wave = tid >> 6;
    const int col  = lane & 15, quad = lane >> 4;
    const int bh   = blockIdx.y, b = bh >> 4, h = bh & 15;
    const int n0   = blockIdx.x * 64;

    // proj -> LDS, 16B-block swizzle kb^(m&7) to spread the stride-128B banks
    for (int i = tid; i < MP_ * 8; i += 256) {
        const int m = i >> 3, c = i & 7;
        *(uint4*)&SB[m * 64 + ((c ^ (m & 7)) << 3)] = *(const uint4*)&projb[m * 64 + (c << 3)];
    }
    for (int i = tid; i < MP_; i += 256) kcl[i] = kcs[(size_t)bh * MP_ + i];
    __syncthreads();

    // dash: C rows n = wave*16 + quad*4 + r, cols m = t*16 + col
    const size_t arow = ((size_t)(b * N_ + n0 + wave * 16 + col)) * DIM_ + h * 64 + quad * 8;
    const s8v af0 = *(const s8v*)&Qb[arow];
    const s8v af1 = *(const s8v*)&Qb[arow + 32];
    const int sw0 = (quad ^ (col & 7)) << 3;          // m&7 == col&7 for rows t*16+col
    const int sw1 = ((quad | 4) ^ (col & 7)) << 3;

    f4v acc[17];
    #pragma unroll
    for (int t = 0; t < 17; ++t) {
        const s8v bf0 = *(const s8v*)&SB[(t * 16 + col) * 64 + sw0];
        const s8v bf1 = *(const s8v*)&SB[(t * 16 + col) * 64 + sw1];
        f4v a = (f4v){0.f, 0.f, 0.f, 0.f};
        a = __builtin_amdgcn_mfma_f32_16x16x32_bf16(af0, bf0, a, 0, 0, 0);
        a = __builtin_amdgcn_mfma_f32_16x16x32_bf16(af1, bf1, a, 0, 0, 0);
        acc[t] = a;
    }

    float dgr[4], rmx[4];
    #pragma unroll
    for (int r = 0; r < 4; ++r) {
        const int gn = n0 + wave * 16 + quad * 4 + r;
        dgr[r] = diagQ[((size_t)(b * N_ + gn)) * H_ + h];
        float mx = -3.4e38f;
        #pragma unroll
        for (int t = 0; t < 16; ++t) mx = fmaxf(mx, acc[t][r]);
        if (col < 10) mx = fmaxf(mx, acc[16][r]);
        mx = fmaxf(mx, __shfl_xor(mx, 1));
        mx = fmaxf(mx, __shfl_xor(mx, 2));
        mx = fmaxf(mx, __shfl_xor(mx, 4));
        mx = fmaxf(mx, __shfl_xor(mx, 8));
        rmx[r] = mx;
    }

    float den[4] = {0.f, 0.f, 0.f, 0.f};
    #pragma unroll
    for (int t = 0; t < 17; ++t) {
        const int m = t * 16 + col;
        const float kc = kcl[m];
        #pragma unroll
        for (int r = 0; r < 4; ++r) {
            float v = 0.f;
            if (m < M_)
                v = RATIOC * (__expf(acc[t][r] - dgr[r] - rmx[r]) + EPSC);
            acc[t][r] = v;
            den[r] += v * kc;
        }
    }

    __syncthreads();   // all proj reads done before SB is overwritten with qp

    // qp -> SB in A-layout-ready form: SB[n][m] stride LSB, zero m in [272,288)
    #pragma unroll
    for (int r = 0; r < 4; ++r) {
        const int rb = (wave * 16 + quad * 4 + r) * LSB;
        #pragma unroll
        for (int t = 0; t < 17; ++t)
            SB[rb + t * 16 + col] = f2bu(acc[t][r]);
        if (col < 8) *(uint*)&SB[rb + 272 + col * 2] = 0u;
    }
    #pragma unroll
    for (int r = 0; r < 4; ++r) {
        float d = den[r];
        d += __shfl_xor(d, 1); d += __shfl_xor(d, 2);
        d += __shfl_xor(d, 4); d += __shfl_xor(d, 8);
        if (col == 0)
            dinv[wave * 16 + quad * 4 + r] = 1.0f / fmaxf(d, 1e-30f);
    }
    __syncthreads();

    // PV: A rows n = wave*16+col (from SB), B rows e = j*16+col from GLOBAL ctxT
    const ushort* ct = ctxT + (size_t)bh * 64 * MP_;
    f4v acc2[4];
    #pragma unroll
    for (int j = 0; j < 4; ++j) acc2[j] = (f4v){0.f, 0.f, 0.f, 0.f};
    #pragma unroll
    for (int kk = 0; kk < 9; ++kk) {
        const s8v afr = *(const s8v*)&SB[(wave * 16 + col) * LSB + kk * 32 + quad * 8];
        #pragma unroll
        for (int j = 0; j < 4; ++j) {
            const s8v bfr = *(const s8v*)&ct[(size_t)(j * 16 + col) * MP_ + kk * 32 + quad * 8];
            acc2[j] = __builtin_amdgcn_mfma_f32_16x16x32_bf16(afr, bfr, acc2[j], 0, 0, 0);
        }
    }
    #pragma unroll
    for (int j = 0; j < 4; ++j) {
        #pragma unroll
        for (int r = 0; r < 4; ++r) {
            const int n = wave * 16 + quad * 4 + r;
            Ab[((size_t)(b * N_ + n0 + n)) * DIM_ + h * 64 + j * 16 + col] =
                f2bu(acc2[j][r] * dinv[n]);
        }
    }
}

// ---------------------------------------------------------------------------
extern "C" void kernel_launch(void* const* d_in, const int* in_sizes, int n_in,
                              void* d_out, int out_size, void* d_ws, size_t ws_size,
                              hipStream_t stream)
{
    const float* x    = (const float*)d_in[0];
    const float* Wq   = (const float*)d_in[1];
    const float* Wk   = (const float*)d_in[2];
    const float* Wv   = (const float*)d_in[3];
    const float* Wo   = (const float*)d_in[4];
    const float* bo   = (const float*)d_in[5];
    const float* proj = (const float*)d_in[6];

    char* ws = (char*)d_ws;
    size_t o = 0;
    ushort* xb    = (ushort*)(ws + o); o += (size_t)RT_ * DIM_ * 2;
    ushort* Wqb   = (ushort*)(ws + o); o += (size_t)DIM_ * DIM_ * 2;
    ushort* Wkb   = (ushort*)(ws + o); o += (size_t)DIM_ * DIM_ * 2;
    ushort* Wvb   = (ushort*)(ws + o); o += (size_t)DIM_ * DIM_ * 2;
    ushort* Wob   = (ushort*)(ws + o); o += (size_t)DIM_ * DIM_ * 2;
    ushort* projb = (ushort*)(ws + o); o += (size_t)MP_ * 64 * 2;
    ushort* Qb    = (ushort*)(ws + o); o += (size_t)RT_ * DIM_ * 2;
    ushort* Kb    = (ushort*)(ws + o); o += (size_t)RT_ * DIM_ * 2;
    ushort* Vb    = (ushort*)(ws + o); o += (size_t)RT_ * DIM_ * 2;
    ushort* Ab    = (ushort*)(ws + o); o += (size_t)RT_ * DIM_ * 2;
    float*    ctxp  = (float*)(ws + o);    o += (size_t)BH_ * NCH * MP_ * 64 * 4;  // 37.75 MB
    float*    kcsp  = (float*)(ws + o);    o += (size_t)BH_ * NCH * MP_ * 4;
    float*    kcs   = (float*)(ws + o);    o += (size_t)BH_ * MP_ * 4;
    unsigned* kmaxb = (unsigned*)(ws + o); o += 128;
    float*    diagQ = (float*)(ws + o);    o += (size_t)RT_ * H_ * 4;
    float*    diagK = (float*)(ws + o);    o += (size_t)RT_ * H_ * 4;
    ushort*   ctxT  = (ushort*)(ws + o);   o += (size_t)BH_ * 64 * MP_ * 2;

    hipMemsetAsync(kmaxb, 0, 128, stream);   // encf(0) < any real max

    cast_x<<<dim3(RT_ * DIM_ / 2048), 256, 0, stream>>>(x, xb);
    cast_w<<<dim3(DIM_ * DIM_ / 2048, 4), 256, 0, stream>>>(Wq, Wk, Wv, Wo, Wqb, Wkb, Wvb, Wob);
    cast_proj<<<dim3(MP_ * 64 / 256), 256, 0, stream>>>(proj, projb);

    const dim3 ggrid(DIM_ / 128, RT_ / 128);   // (8, 64)
    gemm128<true,  false, __hip_bfloat16><<<ggrid, 256, 0, stream>>>(xb, Wqb, nullptr, (__hip_bfloat16*)Qb, diagQ);
    gemm128<true,  false, __hip_bfloat16><<<ggrid, 256, 0, stream>>>(xb, Wkb, nullptr, (__hip_bfloat16*)Kb, diagK);
    gemm128<false, false, __hip_bfloat16><<<ggrid, 256, 0, stream>>>(xb, Wvb, nullptr, (__hip_bfloat16*)Vb, nullptr);

    kmax_mfma<<<dim3(16, BH_), 256, 0, stream>>>(Kb, projb, kmaxb);
    kctx_mfma<<<dim3(NCH, BH_), 256, 0, stream>>>(Kb, Vb, projb, diagK, kmaxb, ctxp, kcsp);
    ctx_reduce<<<dim3(8, BH_), 256, 0, stream>>>(ctxp, kcsp, ctxT, kcs);
    qdashout<<<dim3(N_ / 64, BH_), 256, 0, stream>>>(Qb, projb, diagQ, kcs, ctxT, Ab);

    gemm128<false, true, float><<<ggrid, 256, 0, stream>>>(Ab, Wob, bo, (float*)d_out, nullptr);
}

// Round 2
// 296.223 us; speedup vs baseline: 1.0900x; 1.0869x over previous
//
#include <hip/hip_runtime.h>
#include <hip/hip_bf16.h>
#include <hip/hip_fp16.h>

// Performer (FAVOR+) attention forward — all-MFMA pipeline, v5.
// B=2, N=4096, H=16, D=64, M=266 (padded 288), DIM=1024.
// R9: T14 async-split (early global loads, reg double-buffered PV ctxT
//     reads, next-iter prefetch in kctx/kmax); QKV gemms fused into one
//     1536-block launch (Wq/Wk/Wv contiguous in ws).

#define B_   2
#define N_   4096
#define H_   16
#define M_   266
#define MP_  288     // M padded to 18*16
#define DIM_ 1024
#define RT_  8192    // B_*N_
#define BH_  32      // B_*H_
#define LKN  40      // kctx LDS stride (n-dim 32 padded)
#define LSB  296     // qp LDS row stride (288 + 8)
#define NCH  16      // kctx n-chunks per bh
#define KS_  8       // (N_/NCH)/32

typedef __attribute__((ext_vector_type(8))) short s8v;   // 8 x bf16
typedef __attribute__((ext_vector_type(4))) float f4v;   // MFMA acc

__device__ __forceinline__ ushort f2bu(float x){ __hip_bfloat16 h = __float2bfloat16(x); return *(ushort*)&h; }

constexpr float NORMC  = 0.35355339059327379f;  // 64^-0.25
constexpr float RATIOC = 0.06131393f;           // 266^-0.5
constexpr float DIAGC  = 0.0625f;               // 0.5 * 64^-0.5
constexpr float EPSC   = 1e-4f;

__device__ __forceinline__ unsigned encf(float x){
    unsigned b = __float_as_uint(x);
    return (b & 0x80000000u) ? ~b : (b | 0x80000000u);
}
__device__ __forceinline__ float decf(unsigned u){
    unsigned b = (u & 0x80000000u) ? (u ^ 0x80000000u) : ~u;
    return __uint_as_float(b);
}

__device__ __forceinline__ void stf(float* p, float v){ *p = v; }
__device__ __forceinline__ void stf(__hip_bfloat16* p, float v){ *p = __float2bfloat16(v); }

// async global->LDS, 16B per lane; lds dest wave-uniform base (+lane*16 by HW)
__device__ __forceinline__ void gl_lds16(const ushort* g, ushort* l){
    __builtin_amdgcn_global_load_lds(
        (const __attribute__((address_space(1))) unsigned int*)(const unsigned int*)g,
        (__attribute__((address_space(3))) unsigned int*)(unsigned int*)l,
        16, 0, 0);
}

// ---------------------------------------------------------------------------
// Casts
// ---------------------------------------------------------------------------
__global__ void cast_x(const float* __restrict__ s, ushort* __restrict__ d){
    const int i = (blockIdx.x * 256 + threadIdx.x) * 8;
    const float4 a = *(const float4*)&s[i];
    const float4 b = *(const float4*)&s[i + 4];
    ushort4 lo, hi;
    lo.x = f2bu(a.x); lo.y = f2bu(a.y); lo.z = f2bu(a.z); lo.w = f2bu(a.w);
    hi.x = f2bu(b.x); hi.y = f2bu(b.y); hi.z = f2bu(b.z); hi.w = f2bu(b.w);
    *(ushort4*)&d[i]     = lo;
    *(ushort4*)&d[i + 4] = hi;
}

__global__ void cast_w(const float* s0, const float* s1, const float* s2, const float* s3,
                       ushort* d0, ushort* d1, ushort* d2, ushort* d3){
    const float* s; ushort* d;
    switch (blockIdx.y) {
        case 0: s = s0; d = d0; break;
        case 1: s = s1; d = d1; break;
        case 2: s = s2; d = d2; break;
        default: s = s3; d = d3; break;
    }
    const int i = (blockIdx.x * 256 + threadIdx.x) * 8;
    const float4 a = *(const float4*)&s[i];
    const float4 b = *(const float4*)&s[i + 4];
    ushort4 lo, hi;
    lo.x = f2bu(a.x); lo.y = f2bu(a.y); lo.z = f2bu(a.z); lo.w = f2bu(a.w);
    hi.x = f2bu(b.x); hi.y = f2bu(b.y); hi.z = f2bu(b.z); hi.w = f2bu(b.w);
    *(ushort4*)&d[i]     = lo;
    *(ushort4*)&d[i + 4] = hi;
}

__global__ void cast_proj(const float* __restrict__ p, ushort* __restrict__ pb){
    const int i = blockIdx.x * 256 + threadIdx.x;
    if (i >= MP_ * 64) return;
    const int m = i >> 6, dc = i & 63;
    pb[i] = f2bu((m < M_) ? NORMC * p[m * 64 + dc] : 0.f);
}

// ---------------------------------------------------------------------------
// 128x128 MFMA GEMM with global_load_lds staging (m97 structure).
// ---------------------------------------------------------------------------
template<bool DIAG, bool BIAS, typename TC>
__launch_bounds__(256)
__global__ void gemm128(const ushort* __restrict__ A, const ushort* __restrict__ Bw,
                        const float* __restrict__ bias, TC* __restrict__ C,
                        float* __restrict__ diag)
{
    __shared__ ushort As[128 * 32];
    __shared__ ushort Bs[128 * 32];

    const int tid  = threadIdx.x;
    const int lane = tid & 63, wave = tid >> 6;
    const int col  = lane & 15, quad = lane >> 4;
    const int wm   = (wave & 1) * 64, wn = (wave >> 1) * 64;
    const int r0   = blockIdx.y * 128, c0 = blockIdx.x * 128;

    const int f0 = tid * 8;                       // flat elem offset (16B/lane)
    const int row0 = f0 >> 5, kc0 = f0 & 31;
    const size_t aoff0 = (size_t)(r0 + row0) * DIM_ + kc0;
    const size_t aoff1 = (size_t)(r0 + 64 + row0) * DIM_ + kc0;
    const size_t boff0 = (size_t)(c0 + row0) * DIM_ + kc0;
    const size_t boff1 = (size_t)(c0 + 64 + row0) * DIM_ + kc0;
    ushort* asb0 = &As[wave * 512];        // wave-uniform LDS bases
    ushort* asb1 = &As[2048 + wave * 512];
    ushort* bsb0 = &Bs[wave * 512];
    ushort* bsb1 = &Bs[2048 + wave * 512];

    f4v acc[4][4];
    #pragma unroll
    for (int i = 0; i < 4; ++i)
        #pragma unroll
        for (int j = 0; j < 4; ++j) acc[i][j] = (f4v){0.f, 0.f, 0.f, 0.f};

    for (int kk = 0; kk < DIM_; kk += 32) {
        gl_lds16(&A[aoff0 + kk],  asb0);
        gl_lds16(&A[aoff1 + kk],  asb1);
        gl_lds16(&Bw[boff0 + kk], bsb0);
        gl_lds16(&Bw[boff1 + kk], bsb1);
        __syncthreads();
        s8v af[4], bf[4];
        #pragma unroll
        for (int i = 0; i < 4; ++i)
            af[i] = *(const s8v*)&As[(wm + i * 16 + col) * 32 + quad * 8];
        #pragma unroll
        for (int j = 0; j < 4; ++j)
            bf[j] = *(const s8v*)&Bs[(wn + j * 16 + col) * 32 + quad * 8];
        #pragma unroll
        for (int i = 0; i < 4; ++i)
            #pragma unroll
            for (int j = 0; j < 4; ++j)
                acc[i][j] = __builtin_amdgcn_mfma_f32_16x16x32_bf16(af[i], bf[j], acc[i][j], 0, 0, 0);
        __syncthreads();
    }

    float bb[4] = {0.f, 0.f, 0.f, 0.f};
    if (BIAS) {
        #pragma unroll
        for (int j = 0; j < 4; ++j) bb[j] = bias[c0 + wn + j * 16 + col];
    }
    #pragma unroll
    for (int i = 0; i < 4; ++i) {
        #pragma unroll
        for (int r = 0; r < 4; ++r) {
            const size_t grow = (size_t)(r0 + wm + i * 16 + quad * 4 + r);
            #pragma unroll
            for (int j = 0; j < 4; ++j)
                stf(&C[grow * DIM_ + c0 + wn + j * 16 + col], acc[i][j][r] + bb[j]);
        }
    }
    if (DIAG) {
        const int hglob = (c0 + wn) >> 6;
        #pragma unroll
        for (int i = 0; i < 4; ++i) {
            #pragma unroll
            for (int r = 0; r < 4; ++r) {
                float s = 0.f;
                #pragma unroll
                for (int j = 0; j < 4; ++j) s += acc[i][j][r] * acc[i][j][r];
                s += __shfl_xor(s, 1); s += __shfl_xor(s, 2);
                s += __shfl_xor(s, 4); s += __shfl_xor(s, 8);
                if (col == 0)
                    diag[(size_t)(r0 + wm + i * 16 + quad * 4 + r) * H_ + hglob] = DIAGC * s;
            }
        }
    }
}

// ---------------------------------------------------------------------------
// Fused QKV GEMM: Bw = [Wq;Wk;Wv] (3072 x 1024, contiguous in ws).
// Grid (24, 64). Epilogue routes C/diag by c0>>10.
// ---------------------------------------------------------------------------
__launch_bounds__(256)
__global__ void gemm128_qkv(const ushort* __restrict__ A, const ushort* __restrict__ Bw,
                            ushort* __restrict__ Q, ushort* __restrict__ K,
                            ushort* __restrict__ V,
                            float* __restrict__ diagQ, float* __restrict__ diagK)
{
    __shared__ ushort As[128 * 32];
    __shared__ ushort Bs[128 * 32];

    const int tid  = threadIdx.x;
    const int lane = tid & 63, wave = tid >> 6;
    const int col  = lane & 15, quad = lane >> 4;
    const int wm   = (wave & 1) * 64, wn = (wave >> 1) * 64;
    const int r0   = blockIdx.y * 128, c0 = blockIdx.x * 128;

    const int f0 = tid * 8;
    const int row0 = f0 >> 5, kc0 = f0 & 31;
    const size_t aoff0 = (size_t)(r0 + row0) * DIM_ + kc0;
    const size_t aoff1 = (size_t)(r0 + 64 + row0) * DIM_ + kc0;
    const size_t boff0 = (size_t)(c0 + row0) * DIM_ + kc0;
    const size_t boff1 = (size_t)(c0 + 64 + row0) * DIM_ + kc0;
    ushort* asb0 = &As[wave * 512];
    ushort* asb1 = &As[2048 + wave * 512];
    ushort* bsb0 = &Bs[wave * 512];
    ushort* bsb1 = &Bs[2048 + wave * 512];

    f4v acc[4][4];
    #pragma unroll
    for (int i = 0; i < 4; ++i)
        #pragma unroll
        for (int j = 0; j < 4; ++j) acc[i][j] = (f4v){0.f, 0.f, 0.f, 0.f};

    for (int kk = 0; kk < DIM_; kk += 32) {
        gl_lds16(&A[aoff0 + kk],  asb0);
        gl_lds16(&A[aoff1 + kk],  asb1);
        gl_lds16(&Bw[boff0 + kk], bsb0);
        gl_lds16(&Bw[boff1 + kk], bsb1);
        __syncthreads();
        s8v af[4], bf[4];
        #pragma unroll
        for (int i = 0; i < 4; ++i)
            af[i] = *(const s8v*)&As[(wm + i * 16 + col) * 32 + quad * 8];
        #pragma unroll
        for (int j = 0; j < 4; ++j)
            bf[j] = *(const s8v*)&Bs[(wn + j * 16 + col) * 32 + quad * 8];
        #pragma unroll
        for (int i = 0; i < 4; ++i)
            #pragma unroll
            for (int j = 0; j < 4; ++j)
                acc[i][j] = __builtin_amdgcn_mfma_f32_16x16x32_bf16(af[i], bf[j], acc[i][j], 0, 0, 0);
        __syncthreads();
    }

    const int which = c0 >> 10;           // 0=Q 1=K 2=V (c0 < 3072, 128|1024)
    const int cc    = c0 & 1023;
    ushort* C = (which == 0) ? Q : ((which == 1) ? K : V);
    float* dptr = (which == 0) ? diagQ : ((which == 1) ? diagK : nullptr);

    #pragma unroll
    for (int i = 0; i < 4; ++i) {
        #pragma unroll
        for (int r = 0; r < 4; ++r) {
            const size_t grow = (size_t)(r0 + wm + i * 16 + quad * 4 + r);
            #pragma unroll
            for (int j = 0; j < 4; ++j)
                C[grow * DIM_ + cc + wn + j * 16 + col] = f2bu(acc[i][j][r]);
        }
    }
    if (dptr) {
        const int hglob = (cc + wn) >> 6;
        #pragma unroll
        for (int i = 0; i < 4; ++i) {
            #pragma unroll
            for (int r = 0; r < 4; ++r) {
                float s = 0.f;
                #pragma unroll
                for (int j = 0; j < 4; ++j) s += acc[i][j][r] * acc[i][j][r];
                s += __shfl_xor(s, 1); s += __shfl_xor(s, 2);
                s += __shfl_xor(s, 4); s += __shfl_xor(s, 8);
                if (col == 0)
                    dptr[(size_t)(r0 + wm + i * 16 + quad * 4 + r) * H_ + hglob] = DIAGC * s;
            }
        }
    }
}

// ---------------------------------------------------------------------------
// Pass 1: global max over (n,m) of kdash per bh. Grid (16, 32).
// proj LDS tile XOR-swizzled; next-ni K rows prefetched during MFMA t-loop.
// ---------------------------------------------------------------------------
__launch_bounds__(256)
__global__ void kmax_mfma(const ushort* __restrict__ Kb, const ushort* __restrict__ projb,
                          unsigned* __restrict__ kmaxb)
{
    __shared__ ushort Pl[MP_ * 64];   // 36864 B
    __shared__ float wmx[4];
    const int tid  = threadIdx.x;
    const int lane = tid & 63, wave = tid >> 6;
    const int col  = lane & 15, quad = lane >> 4;
    const int bh   = blockIdx.y, b = bh >> 4, h = bh & 15;

    // early: issue first K-row loads before staging barrier
    const size_t arowB = ((size_t)(b * N_ + blockIdx.x * 256 + wave * 16 + col)) * DIM_ + h * 64 + quad * 8;
    s8v aP0 = *(const s8v*)&Kb[arowB];
    s8v aP1 = *(const s8v*)&Kb[arowB + 32];

    for (int i = tid; i < MP_ * 8; i += 256) {
        const int m = i >> 3, c = i & 7;
        *(uint4*)&Pl[m * 64 + ((c ^ (m & 7)) << 3)] = *(const uint4*)&projb[m * 64 + (c << 3)];
    }
    __syncthreads();

    const int sw0 = (quad ^ (col & 7)) << 3;          // m&7 == col&7 (rows t*16+col)
    const int sw1 = ((quad | 4) ^ (col & 7)) << 3;

    float mx = -3.4e38f;
    #pragma unroll
    for (int ni = 0; ni < 4; ++ni) {
        const s8v af0 = aP0, af1 = aP1;
        if (ni < 3) {
            aP0 = *(const s8v*)&Kb[arowB + (size_t)(ni + 1) * 64 * DIM_];
            aP1 = *(const s8v*)&Kb[arowB + (size_t)(ni + 1) * 64 * DIM_ + 32];
        }
        #pragma unroll
        for (int t = 0; t < 17; ++t) {
            const s8v bf0 = *(const s8v*)&Pl[(t * 16 + col) * 64 + sw0];
            const s8v bf1 = *(const s8v*)&Pl[(t * 16 + col) * 64 + sw1];
            f4v a = (f4v){0.f, 0.f, 0.f, 0.f};
            a = __builtin_amdgcn_mfma_f32_16x16x32_bf16(af0, bf0, a, 0, 0, 0);
            a = __builtin_amdgcn_mfma_f32_16x16x32_bf16(af1, bf1, a, 0, 0, 0);
            if (t * 16 + col < M_) {
                #pragma unroll
                for (int r = 0; r < 4; ++r) mx = fmaxf(mx, a[r]);
            }
        }
    }
    #pragma unroll
    for (int o = 32; o > 0; o >>= 1) mx = fmaxf(mx, __shfl_xor(mx, o));
    if (lane == 0) wmx[wave] = mx;
    __syncthreads();
    if (tid == 0)
        atomicMax(&kmaxb[bh], encf(fmaxf(fmaxf(wmx[0], wmx[1]), fmaxf(wmx[2], wmx[3]))));
}

// ---------------------------------------------------------------------------
// Pass 2: partial ctx/kcs per n-chunk, NO atomics. Grid (NCH, 32).
// Next-ks K/V/diag registers prefetched before ctx-MFMA barrier (T14).
// ---------------------------------------------------------------------------
__launch_bounds__(256)
__global__ void kctx_mfma(const ushort* __restrict__ Kb, const ushort* __restrict__ Vb,
                          const ushort* __restrict__ projb,
                          const float* __restrict__ diagK, const unsigned* __restrict__ kmaxb,
                          float* __restrict__ ctxp, float* __restrict__ kcsp)
{
    __shared__ ushort Pl[MP_ * 64];    // 36864 B (proj, resident, swizzled)
    __shared__ ushort Kp[MP_ * LKN];   // 23040 B (kp^T tile [m][n32])
    __shared__ ushort Vt[64 * LKN];    //  5120 B (V^T tile [e][n32])
    __shared__ float kred[2][MP_];     //  2304 B

    const int tid  = threadIdx.x;
    const int lane = tid & 63, wave = tid >> 6;
    const int col  = lane & 15, quad = lane >> 4;
    const int bh   = blockIdx.y, b = bh >> 4, h = bh & 15;
    const int n0   = blockIdx.x * (N_ / NCH);
    const float kmax = decf(kmaxb[bh]);
    const int rowblk = wave >> 1;            // waves 0,1 -> n-rows 0-15; 2,3 -> 16-31
    const int t0 = (wave & 1) * 9;           // m-tiles: 0..8 / 9..17 (covers all 18)

    // early: prologue loads for ks=0 (before staging barrier)
    const int nst = tid & 31, est = (tid >> 5) * 8;
    s8v vvP = *(const s8v*)&Vb[((size_t)(b * N_ + n0 + nst)) * DIM_ + h * 64 + est];
    const size_t arow0 = ((size_t)(b * N_ + n0 + rowblk * 16 + col)) * DIM_ + h * 64 + quad * 8;
    s8v afP0 = *(const s8v*)&Kb[arow0];
    s8v afP1 = *(const s8v*)&Kb[arow0 + 32];
    float dgrP[4];
    #pragma unroll
    for (int r = 0; r < 4; ++r)
        dgrP[r] = diagK[((size_t)(b * N_ + n0 + rowblk * 16 + quad * 4 + r)) * H_ + h];

    for (int i = tid; i < MP_ * 8; i += 256) {
        const int m = i >> 3, c = i & 7;
        *(uint4*)&Pl[m * 64 + ((c ^ (m & 7)) << 3)] = *(const uint4*)&projb[m * 64 + (c << 3)];
    }
    const int sw0 = (quad ^ (col & 7)) << 3;
    const int sw1 = ((quad | 4) ^ (col & 7)) << 3;

    f4v facc[18];
    #pragma unroll
    for (int t = 0; t < 18; ++t) facc[t] = (f4v){0.f, 0.f, 0.f, 0.f};
    float kcsa[9] = {};

    __syncthreads();

    for (int ks = 0; ks < KS_; ++ks) {
        const s8v vv = vvP, af0 = afP0, af1 = afP1;
        float dgr[4];
        #pragma unroll
        for (int r = 0; r < 4; ++r) dgr[r] = dgrP[r];

        // V^T stage from prefetched regs
        #pragma unroll
        for (int j = 0; j < 8; ++j) Vt[(est + j) * LKN + nst] = ((const ushort*)&vv)[j];

        for (int t = t0; t < t0 + 9; ++t) {
            const s8v bf0 = *(const s8v*)&Pl[(t * 16 + col) * 64 + sw0];
            const s8v bf1 = *(const s8v*)&Pl[(t * 16 + col) * 64 + sw1];
            f4v a = (f4v){0.f, 0.f, 0.f, 0.f};
            a = __builtin_amdgcn_mfma_f32_16x16x32_bf16(af0, bf0, a, 0, 0, 0);
            a = __builtin_amdgcn_mfma_f32_16x16x32_bf16(af1, bf1, a, 0, 0, 0);
            const int m = t * 16 + col;
            float kp[4];
            #pragma unroll
            for (int r = 0; r < 4; ++r) {
                float v = 0.f;
                if (m < M_) v = RATIOC * (__expf(a[r] - dgr[r] - kmax) + EPSC);
                kp[r] = v;
            }
            kcsa[t - t0] += kp[0] + kp[1] + kp[2] + kp[3];
            ushort4 pk;
            pk.x = f2bu(kp[0]); pk.y = f2bu(kp[1]); pk.z = f2bu(kp[2]); pk.w = f2bu(kp[3]);
            *(ushort4*)&Kp[m * LKN + rowblk * 16 + quad * 4] = pk;   // 4 consecutive n
        }

        // prefetch ks+1 (flies across both barriers + ctx MFMAs)
        if (ks + 1 < KS_) {
            const int nb1 = n0 + (ks + 1) * 32;
            vvP  = *(const s8v*)&Vb[((size_t)(b * N_ + nb1 + nst)) * DIM_ + h * 64 + est];
            const size_t arow1 = ((size_t)(b * N_ + nb1 + rowblk * 16 + col)) * DIM_ + h * 64 + quad * 8;
            afP0 = *(const s8v*)&Kb[arow1];
            afP1 = *(const s8v*)&Kb[arow1 + 32];
            #pragma unroll
            for (int r = 0; r < 4; ++r)
                dgrP[r] = diagK[((size_t)(b * N_ + nb1 + rowblk * 16 + quad * 4 + r)) * H_ + h];
        }
        __syncthreads();
        // out: wave owns e-tile = wave*16, all 18 m-tiles, k = 32 (this chunk)
        const s8v bfe = *(const s8v*)&Vt[(wave * 16 + col) * LKN + quad * 8];
        #pragma unroll
        for (int t = 0; t < 18; ++t) {
            const s8v am = *(const s8v*)&Kp[(t * 16 + col) * LKN + quad * 8];
            facc[t] = __builtin_amdgcn_mfma_f32_16x16x32_bf16(am, bfe, facc[t], 0, 0, 0);
        }
        __syncthreads();
    }

    // partial ctx: plain stores (D layout: m = t*16+quad*4+r, e = wave*16+col)
    const size_t pbase = ((size_t)bh * NCH + blockIdx.x) * (MP_ * 64);
    #pragma unroll
    for (int t = 0; t < 18; ++t) {
        #pragma unroll
        for (int r = 0; r < 4; ++r)
            ctxp[pbase + (size_t)(t * 16 + quad * 4 + r) * 64 + wave * 16 + col] = facc[t][r];
    }
    // partial kcs via LDS combine (waves 0/1 -> kred[0], 2/3 -> kred[1])
    for (int t = t0; t < t0 + 9; ++t) {
        float s = kcsa[t - t0];
        s += __shfl_xor(s, 16);
        s += __shfl_xor(s, 32);
        if (quad == 0) kred[rowblk][t * 16 + col] = s;
    }
    __syncthreads();
    for (int i = tid; i < MP_; i += 256)
        kcsp[((size_t)bh * NCH + blockIdx.x) * MP_ + i] = kred[0][i] + kred[1][i];
}

// ---------------------------------------------------------------------------
// Reduce partials: ctxT[bh][e][m] (bf16) + kcs[bh][m]. Grid (8, 32).
// ---------------------------------------------------------------------------
__launch_bounds__(256)
__global__ void ctx_reduce(const float* __restrict__ ctxp, const float* __restrict__ kcsp,
                           ushort* __restrict__ ctxT, float* __restrict__ kcs)
{
    const int bh = blockIdx.y, tid = threadIdx.x;
    const int base = blockIdx.x * (MP_ * 64 / 8);   // 2304
    const size_t cb = (size_t)bh * NCH * (MP_ * 64);
    #pragma unroll
    for (int u = 0; u < 9; ++u) {
        const int flat = base + u * 256 + tid;
        float s = 0.f;
        #pragma unroll
        for (int c = 0; c < NCH; ++c) s += ctxp[cb + (size_t)c * (MP_ * 64) + flat];
        const int m = flat >> 6, e = flat & 63;
        ctxT[((size_t)bh * 64 + e) * MP_ + m] = f2bu(s);
    }
    if (blockIdx.x == 0) {
        for (int i = tid; i < MP_; i += 256) {
            float s = 0.f;
            #pragma unroll
            for (int c = 0; c < NCH; ++c) s += kcsp[((size_t)bh * NCH + c) * MP_ + i];
            kcs[(size_t)bh * MP_ + i] = s;
        }
    }
}

// ---------------------------------------------------------------------------
// Fused Q path, v5: early Qb/diag loads (above staging barrier); PV ctxT
// B-frags register-double-buffered with kk=0/1 issued before the transpose
// barriers (T14). Grid (64, 32).
// ---------------------------------------------------------------------------
__launch_bounds__(256)
__global__ void qdashout(const ushort* __restrict__ Qb, const ushort* __restrict__ projb,
                         const float* __restrict__ diagQ, const float* __restrict__ kcs,
                         const ushort* __restrict__ ctxT, ushort* __restrict__ Ab)
{
    __shared__ ushort SB[64 * LSB];   // 37888 B: proj swizzled [m][64] (18432) then qp [n][LSB]
    __shared__ float kcl[MP_];
    __shared__ float dinv[64];

    const int tid  = threadIdx.x;
    const int lane = tid & 63, wave = tid >> 6;
    const int col  = lane & 15, quad = lane >> 4;
    const int bh   = blockIdx.y, b = bh >> 4, h = bh & 15;
    const int n0   = blockIdx.x * 64;

    // early: issue Qb row loads + diagQ before the staging barrier
    const size_t arow = ((size_t)(b * N_ + n0 + wave * 16 + col)) * DIM_ + h * 64 + quad * 8;
    const s8v af0 = *(const s8v*)&Qb[arow];
    const s8v af1 = *(const s8v*)&Qb[arow + 32];
    float dgr[4];
    #pragma unroll
    for (int r = 0; r < 4; ++r)
        dgr[r] = diagQ[((size_t)(b * N_ + n0 + wave * 16 + quad * 4 + r)) * H_ + h];

    // proj -> LDS, 16B-block swizzle kb^(m&7) to spread the stride-128B banks
    for (int i = tid; i < MP_ * 8; i += 256) {
        const int m = i >> 3, c = i & 7;
        *(uint4*)&SB[m * 64 + ((c ^ (m & 7)) << 3)] = *(const uint4*)&projb[m * 64 + (c << 3)];
    }
    for (int i = tid; i < MP_; i += 256) kcl[i] = kcs[(size_t)bh * MP_ + i];
    __syncthreads();

    // dash: C rows n = wave*16 + quad*4 + r, cols m = t*16 + col
    const int sw0 = (quad ^ (col & 7)) << 3;          // m&7 == col&7 for rows t*16+col
    const int sw1 = ((quad | 4) ^ (col & 7)) << 3;

    f4v acc[17];
    #pragma unroll
    for (int t = 0; t < 17; ++t) {
        const s8v bf0 = *(const s8v*)&SB[(t * 16 + col) * 64 + sw0];
        const s8v bf1 = *(const s8v*)&SB[(t * 16 + col) * 64 + sw1];
        f4v a = (f4v){0.f, 0.f, 0.f, 0.f};
        a = __builtin_amdgcn_mfma_f32_16x16x32_bf16(af0, bf0, a, 0, 0, 0);
        a = __builtin_amdgcn_mfma_f32_16x16x32_bf16(af1, bf1, a, 0, 0, 0);
        acc[t] = a;
    }

    float rmx[4];
    #pragma unroll
    for (int r = 0; r < 4; ++r) {
        float mx = -3.4e38f;
        #pragma unroll
        for (int t = 0; t < 16; ++t) mx = fmaxf(mx, acc[t][r]);
        if (col < 10) mx = fmaxf(mx, acc[16][r]);
        mx = fmaxf(mx, __shfl_xor(mx, 1));
        mx = fmaxf(mx, __shfl_xor(mx, 2));
        mx = fmaxf(mx, __shfl_xor(mx, 4));
        mx = fmaxf(mx, __shfl_xor(mx, 8));
        rmx[r] = mx;
    }

    float den[4] = {0.f, 0.f, 0.f, 0.f};
    #pragma unroll
    for (int t = 0; t < 17; ++t) {
        const int m = t * 16 + col;
        const float kc = kcl[m];
        #pragma unroll
        for (int r = 0; r < 4; ++r) {
            float v = 0.f;
            if (m < M_)
                v = RATIOC * (__expf(acc[t][r] - dgr[r] - rmx[r]) + EPSC);
            acc[t][r] = v;
            den[r] += v * kc;
        }
    }

    // T14 issue-early: PV B-frags for kk=0 fly across the 2 barriers below
    const ushort* ct = ctxT + (size_t)bh * 64 * MP_;
    s8v bfA[4], bfB[4];
    #pragma unroll
    for (int j = 0; j < 4; ++j)
        bfA[j] = *(const s8v*)&ct[(size_t)(j * 16 + col) * MP_ + quad * 8];

    __syncthreads();   // all proj reads done before SB is overwritten with qp

    // qp -> SB in A-layout-ready form: SB[n][m] stride LSB, zero m in [272,288)
    #pragma unroll
    for (int r = 0; r < 4; ++r) {
        const int rb = (wave * 16 + quad * 4 + r) * LSB;
        #pragma unroll
        for (int t = 0; t < 17; ++t)
            SB[rb + t * 16 + col] = f2bu(acc[t][r]);
        if (col < 8) *(uint*)&SB[rb + 272 + col * 2] = 0u;
    }
    #pragma unroll
    for (int r = 0; r < 4; ++r) {
        float d = den[r];
        d += __shfl_xor(d, 1); d += __shfl_xor(d, 2);
        d += __shfl_xor(d, 4); d += __shfl_xor(d, 8);
        if (col == 0)
            dinv[wave * 16 + quad * 4 + r] = 1.0f / fmaxf(d, 1e-30f);
    }
    __syncthreads();

    // PV: A rows n = wave*16+col (from SB), B rows e = j*16+col from GLOBAL
    // ctxT, register-double-buffered (all indices compile-time).
    f4v acc2[4];
    #pragma unroll
    for (int j = 0; j < 4; ++j) acc2[j] = (f4v){0.f, 0.f, 0.f, 0.f};
    #pragma unroll
    for (int kp = 0; kp < 4; ++kp) {
        const int k0 = 2 * kp, k1 = 2 * kp + 1, k2 = 2 * kp + 2;
        #pragma unroll
        for (int j = 0; j < 4; ++j)
            bfB[j] = *(const s8v*)&ct[(size_t)(j * 16 + col) * MP_ + k1 * 32 + quad * 8];
        const s8v afrA = *(const s8v*)&SB[(wave * 16 + col) * LSB + k0 * 32 + quad * 8];
        #pragma unroll
        for (int j = 0; j < 4; ++j)
            acc2[j] = __builtin_amdgcn_mfma_f32_16x16x32_bf16(afrA, bfA[j], acc2[j], 0, 0, 0);
        #pragma unroll
        for (int j = 0; j < 4; ++j)
            bfA[j] = *(const s8v*)&ct[(size_t)(j * 16 + col) * MP_ + k2 * 32 + quad * 8];
        const s8v afrB = *(const s8v*)&SB[(wave * 16 + col) * LSB + k1 * 32 + quad * 8];
        #pragma unroll
        for (int j = 0; j < 4; ++j)
            acc2[j] = __builtin_amdgcn_mfma_f32_16x16x32_bf16(afrB, bfB[j], acc2[j], 0, 0, 0);
    }
    {   // kk = 8 tail (bfA holds it)
        const s8v afrT = *(const s8v*)&SB[(wave * 16 + col) * LSB + 8 * 32 + quad * 8];
        #pragma unroll
        for (int j = 0; j < 4; ++j)
            acc2[j] = __builtin_amdgcn_mfma_f32_16x16x32_bf16(afrT, bfA[j], acc2[j], 0, 0, 0);
    }
    #pragma unroll
    for (int j = 0; j < 4; ++j) {
        #pragma unroll
        for (int r = 0; r < 4; ++r) {
            const int n = wave * 16 + quad * 4 + r;
            Ab[((size_t)(b * N_ + n0 + n)) * DIM_ + h * 64 + j * 16 + col] =
                f2bu(acc2[j][r] * dinv[n]);
        }
    }
}

// ---------------------------------------------------------------------------
extern "C" void kernel_launch(void* const* d_in, const int* in_sizes, int n_in,
                              void* d_out, int out_size, void* d_ws, size_t ws_size,
                              hipStream_t stream)
{
    const float* x    = (const float*)d_in[0];
    const float* Wq   = (const float*)d_in[1];
    const float* Wk   = (const float*)d_in[2];
    const float* Wv   = (const float*)d_in[3];
    const float* Wo   = (const float*)d_in[4];
    const float* bo   = (const float*)d_in[5];
    const float* proj = (const float*)d_in[6];

    char* ws = (char*)d_ws;
    size_t o = 0;
    ushort* xb    = (ushort*)(ws + o); o += (size_t)RT_ * DIM_ * 2;
    ushort* Wqb   = (ushort*)(ws + o); o += (size_t)DIM_ * DIM_ * 2;   // Wq;Wk;Wv contiguous
    ushort* Wkb   = (ushort*)(ws + o); o += (size_t)DIM_ * DIM_ * 2;
    ushort* Wvb   = (ushort*)(ws + o); o += (size_t)DIM_ * DIM_ * 2;
    ushort* Wob   = (ushort*)(ws + o); o += (size_t)DIM_ * DIM_ * 2;
    ushort* projb = (ushort*)(ws + o); o += (size_t)MP_ * 64 * 2;
    ushort* Qb    = (ushort*)(ws + o); o += (size_t)RT_ * DIM_ * 2;
    ushort* Kb    = (ushort*)(ws + o); o += (size_t)RT_ * DIM_ * 2;
    ushort* Vb    = (ushort*)(ws + o); o += (size_t)RT_ * DIM_ * 2;
    ushort* Ab    = (ushort*)(ws + o); o += (size_t)RT_ * DIM_ * 2;
    float*    ctxp  = (float*)(ws + o);    o += (size_t)BH_ * NCH * MP_ * 64 * 4;  // 37.75 MB
    float*    kcsp  = (float*)(ws + o);    o += (size_t)BH_ * NCH * MP_ * 4;
    float*    kcs   = (float*)(ws + o);    o += (size_t)BH_ * MP_ * 4;
    unsigned* kmaxb = (unsigned*)(ws + o); o += 128;
    float*    diagQ = (float*)(ws + o);    o += (size_t)RT_ * H_ * 4;
    float*    diagK = (float*)(ws + o);    o += (size_t)RT_ * H_ * 4;
    ushort*   ctxT  = (ushort*)(ws + o);   o += (size_t)BH_ * 64 * MP_ * 2;

    hipMemsetAsync(kmaxb, 0, 128, stream);   // encf(0) < any real max

    cast_x<<<dim3(RT_ * DIM_ / 2048), 256, 0, stream>>>(x, xb);
    cast_w<<<dim3(DIM_ * DIM_ / 2048, 4), 256, 0, stream>>>(Wq, Wk, Wv, Wo, Wqb, Wkb, Wvb, Wob);
    cast_proj<<<dim3(MP_ * 64 / 256), 256, 0, stream>>>(proj, projb);

    // fused QKV: B = [Wq;Wk;Wv] = 3072x1024 (contiguous), grid 24x64
    gemm128_qkv<<<dim3(24, RT_ / 128), 256, 0, stream>>>(xb, Wqb, Qb, Kb, Vb, diagQ, diagK);

    kmax_mfma<<<dim3(16, BH_), 256, 0, stream>>>(Kb, projb, kmaxb);
    kctx_mfma<<<dim3(NCH, BH_), 256, 0, stream>>>(Kb, Vb, projb, diagK, kmaxb, ctxp, kcsp);
    ctx_reduce<<<dim3(8, BH_), 256, 0, stream>>>(ctxp, kcsp, ctxT, kcs);
    qdashout<<<dim3(N_ / 64, BH_), 256, 0, stream>>>(Qb, projb, diagQ, kcs, ctxT, Ab);

    gemm128<false, true, float><<<dim3(DIM_ / 128, RT_ / 128), 256, 0, stream>>>(Ab, Wob, bo, (float*)d_out, nullptr);
}

// Round 3
// 278.404 us; speedup vs baseline: 1.1598x; 1.0640x over previous
//
#include <hip/hip_runtime.h>
#include <hip/hip_bf16.h>
#include <hip/hip_fp16.h>

// Performer (FAVOR+) attention forward — all-MFMA pipeline, v6.
// B=2, N=4096, H=16, D=64, M=266 (padded 288), DIM=1024.
// R10: kmax_mfma eliminated — kctx computes chunk-local max (phase A over
//      its own L2-warm K rows) and stores UNSCALED exp partials; ctx_reduce
//      rescales exactly (e^{m_c-M}) and adds the separable EPS rank-1 term
//      (needs Vsum, accumulated free in kctx). XCD-aware block swizzle (T1)
//      on both GEMMs (1536 and 512 blocks, both %8==0 -> bijective).

#define B_   2
#define N_   4096
#define H_   16
#define M_   266
#define MP_  288     // M padded to 18*16
#define DIM_ 1024
#define RT_  8192    // B_*N_
#define BH_  32      // B_*H_
#define LKN  40      // kctx LDS stride (n-dim 32 padded)
#define LSB  296     // qp LDS row stride (288 + 8)
#define NCH  16      // kctx n-chunks per bh
#define KS_  8       // (N_/NCH)/32

typedef __attribute__((ext_vector_type(8))) short s8v;   // 8 x bf16
typedef __attribute__((ext_vector_type(4))) float f4v;   // MFMA acc

__device__ __forceinline__ ushort f2bu(float x){ __hip_bfloat16 h = __float2bfloat16(x); return *(ushort*)&h; }
__device__ __forceinline__ float  bu2f(ushort u){ return __uint_as_float(((unsigned)u) << 16); }

constexpr float NORMC  = 0.35355339059327379f;  // 64^-0.25
constexpr float RATIOC = 0.06131393f;           // 266^-0.5
constexpr float DIAGC  = 0.0625f;               // 0.5 * 64^-0.5
constexpr float EPSC   = 1e-4f;

__device__ __forceinline__ void stf(float* p, float v){ *p = v; }
__device__ __forceinline__ void stf(__hip_bfloat16* p, float v){ *p = __float2bfloat16(v); }

// async global->LDS, 16B per lane; lds dest wave-uniform base (+lane*16 by HW)
__device__ __forceinline__ void gl_lds16(const ushort* g, ushort* l){
    __builtin_amdgcn_global_load_lds(
        (const __attribute__((address_space(1))) unsigned int*)(const unsigned int*)g,
        (__attribute__((address_space(3))) unsigned int*)(unsigned int*)l,
        16, 0, 0);
}

// ---------------------------------------------------------------------------
// Casts
// ---------------------------------------------------------------------------
__global__ void cast_x(const float* __restrict__ s, ushort* __restrict__ d){
    const int i = (blockIdx.x * 256 + threadIdx.x) * 8;
    const float4 a = *(const float4*)&s[i];
    const float4 b = *(const float4*)&s[i + 4];
    ushort4 lo, hi;
    lo.x = f2bu(a.x); lo.y = f2bu(a.y); lo.z = f2bu(a.z); lo.w = f2bu(a.w);
    hi.x = f2bu(b.x); hi.y = f2bu(b.y); hi.z = f2bu(b.z); hi.w = f2bu(b.w);
    *(ushort4*)&d[i]     = lo;
    *(ushort4*)&d[i + 4] = hi;
}

__global__ void cast_w(const float* s0, const float* s1, const float* s2, const float* s3,
                       ushort* d0, ushort* d1, ushort* d2, ushort* d3){
    const float* s; ushort* d;
    switch (blockIdx.y) {
        case 0: s = s0; d = d0; break;
        case 1: s = s1; d = d1; break;
        case 2: s = s2; d = d2; break;
        default: s = s3; d = d3; break;
    }
    const int i = (blockIdx.x * 256 + threadIdx.x) * 8;
    const float4 a = *(const float4*)&s[i];
    const float4 b = *(const float4*)&s[i + 4];
    ushort4 lo, hi;
    lo.x = f2bu(a.x); lo.y = f2bu(a.y); lo.z = f2bu(a.z); lo.w = f2bu(a.w);
    hi.x = f2bu(b.x); hi.y = f2bu(b.y); hi.z = f2bu(b.z); hi.w = f2bu(b.w);
    *(ushort4*)&d[i]     = lo;
    *(ushort4*)&d[i + 4] = hi;
}

__global__ void cast_proj(const float* __restrict__ p, ushort* __restrict__ pb){
    const int i = blockIdx.x * 256 + threadIdx.x;
    if (i >= MP_ * 64) return;
    const int m = i >> 6, dc = i & 63;
    pb[i] = f2bu((m < M_) ? NORMC * p[m * 64 + dc] : 0.f);
}

// ---------------------------------------------------------------------------
// 128x128 MFMA GEMM with global_load_lds staging (m97 structure) + T1 swizzle.
// ---------------------------------------------------------------------------
template<bool DIAG, bool BIAS, typename TC>
__launch_bounds__(256)
__global__ void gemm128(const ushort* __restrict__ A, const ushort* __restrict__ Bw,
                        const float* __restrict__ bias, TC* __restrict__ C,
                        float* __restrict__ diag)
{
    __shared__ ushort As[128 * 32];
    __shared__ ushort Bs[128 * 32];

    const int tid  = threadIdx.x;
    const int lane = tid & 63, wave = tid >> 6;
    const int col  = lane & 15, quad = lane >> 4;
    const int wm   = (wave & 1) * 64, wn = (wave >> 1) * 64;

    // T1: XCD-aware bijective swizzle (grid total % 8 == 0)
    const int gX = gridDim.x, total = gX * gridDim.y, cpx = total >> 3;
    const int fl = blockIdx.x + blockIdx.y * gX;
    const int sw = (fl & 7) * cpx + (fl >> 3);
    const int r0 = (sw / gX) * 128, c0 = (sw % gX) * 128;

    const int f0 = tid * 8;                       // flat elem offset (16B/lane)
    const int row0 = f0 >> 5, kc0 = f0 & 31;
    const size_t aoff0 = (size_t)(r0 + row0) * DIM_ + kc0;
    const size_t aoff1 = (size_t)(r0 + 64 + row0) * DIM_ + kc0;
    const size_t boff0 = (size_t)(c0 + row0) * DIM_ + kc0;
    const size_t boff1 = (size_t)(c0 + 64 + row0) * DIM_ + kc0;
    ushort* asb0 = &As[wave * 512];        // wave-uniform LDS bases
    ushort* asb1 = &As[2048 + wave * 512];
    ushort* bsb0 = &Bs[wave * 512];
    ushort* bsb1 = &Bs[2048 + wave * 512];

    f4v acc[4][4];
    #pragma unroll
    for (int i = 0; i < 4; ++i)
        #pragma unroll
        for (int j = 0; j < 4; ++j) acc[i][j] = (f4v){0.f, 0.f, 0.f, 0.f};

    for (int kk = 0; kk < DIM_; kk += 32) {
        gl_lds16(&A[aoff0 + kk],  asb0);
        gl_lds16(&A[aoff1 + kk],  asb1);
        gl_lds16(&Bw[boff0 + kk], bsb0);
        gl_lds16(&Bw[boff1 + kk], bsb1);
        __syncthreads();
        s8v af[4], bf[4];
        #pragma unroll
        for (int i = 0; i < 4; ++i)
            af[i] = *(const s8v*)&As[(wm + i * 16 + col) * 32 + quad * 8];
        #pragma unroll
        for (int j = 0; j < 4; ++j)
            bf[j] = *(const s8v*)&Bs[(wn + j * 16 + col) * 32 + quad * 8];
        #pragma unroll
        for (int i = 0; i < 4; ++i)
            #pragma unroll
            for (int j = 0; j < 4; ++j)
                acc[i][j] = __builtin_amdgcn_mfma_f32_16x16x32_bf16(af[i], bf[j], acc[i][j], 0, 0, 0);
        __syncthreads();
    }

    float bb[4] = {0.f, 0.f, 0.f, 0.f};
    if (BIAS) {
        #pragma unroll
        for (int j = 0; j < 4; ++j) bb[j] = bias[c0 + wn + j * 16 + col];
    }
    #pragma unroll
    for (int i = 0; i < 4; ++i) {
        #pragma unroll
        for (int r = 0; r < 4; ++r) {
            const size_t grow = (size_t)(r0 + wm + i * 16 + quad * 4 + r);
            #pragma unroll
            for (int j = 0; j < 4; ++j)
                stf(&C[grow * DIM_ + c0 + wn + j * 16 + col], acc[i][j][r] + bb[j]);
        }
    }
    if (DIAG) {
        const int hglob = (c0 + wn) >> 6;
        #pragma unroll
        for (int i = 0; i < 4; ++i) {
            #pragma unroll
            for (int r = 0; r < 4; ++r) {
                float s = 0.f;
                #pragma unroll
                for (int j = 0; j < 4; ++j) s += acc[i][j][r] * acc[i][j][r];
                s += __shfl_xor(s, 1); s += __shfl_xor(s, 2);
                s += __shfl_xor(s, 4); s += __shfl_xor(s, 8);
                if (col == 0)
                    diag[(size_t)(r0 + wm + i * 16 + quad * 4 + r) * H_ + hglob] = DIAGC * s;
            }
        }
    }
}

// ---------------------------------------------------------------------------
// Fused QKV GEMM: Bw = [Wq;Wk;Wv] (3072 x 1024, contiguous in ws).
// Grid (24, 64). T1 swizzle; epilogue routes C/diag by c0>>10.
// ---------------------------------------------------------------------------
__launch_bounds__(256)
__global__ void gemm128_qkv(const ushort* __restrict__ A, const ushort* __restrict__ Bw,
                            ushort* __restrict__ Q, ushort* __restrict__ K,
                            ushort* __restrict__ V,
                            float* __restrict__ diagQ, float* __restrict__ diagK)
{
    __shared__ ushort As[128 * 32];
    __shared__ ushort Bs[128 * 32];

    const int tid  = threadIdx.x;
    const int lane = tid & 63, wave = tid >> 6;
    const int col  = lane & 15, quad = lane >> 4;
    const int wm   = (wave & 1) * 64, wn = (wave >> 1) * 64;

    // T1 swizzle: 1536 blocks, 8 XCDs -> chunks of 192
    const int fl = blockIdx.x + blockIdx.y * 24;
    const int sw = (fl & 7) * 192 + (fl >> 3);
    const int r0 = (sw / 24) * 128, c0 = (sw % 24) * 128;

    const int f0 = tid * 8;
    const int row0 = f0 >> 5, kc0 = f0 & 31;
    const size_t aoff0 = (size_t)(r0 + row0) * DIM_ + kc0;
    const size_t aoff1 = (size_t)(r0 + 64 + row0) * DIM_ + kc0;
    const size_t boff0 = (size_t)(c0 + row0) * DIM_ + kc0;
    const size_t boff1 = (size_t)(c0 + 64 + row0) * DIM_ + kc0;
    ushort* asb0 = &As[wave * 512];
    ushort* asb1 = &As[2048 + wave * 512];
    ushort* bsb0 = &Bs[wave * 512];
    ushort* bsb1 = &Bs[2048 + wave * 512];

    f4v acc[4][4];
    #pragma unroll
    for (int i = 0; i < 4; ++i)
        #pragma unroll
        for (int j = 0; j < 4; ++j) acc[i][j] = (f4v){0.f, 0.f, 0.f, 0.f};

    for (int kk = 0; kk < DIM_; kk += 32) {
        gl_lds16(&A[aoff0 + kk],  asb0);
        gl_lds16(&A[aoff1 + kk],  asb1);
        gl_lds16(&Bw[boff0 + kk], bsb0);
        gl_lds16(&Bw[boff1 + kk], bsb1);
        __syncthreads();
        s8v af[4], bf[4];
        #pragma unroll
        for (int i = 0; i < 4; ++i)
            af[i] = *(const s8v*)&As[(wm + i * 16 + col) * 32 + quad * 8];
        #pragma unroll
        for (int j = 0; j < 4; ++j)
            bf[j] = *(const s8v*)&Bs[(wn + j * 16 + col) * 32 + quad * 8];
        #pragma unroll
        for (int i = 0; i < 4; ++i)
            #pragma unroll
            for (int j = 0; j < 4; ++j)
                acc[i][j] = __builtin_amdgcn_mfma_f32_16x16x32_bf16(af[i], bf[j], acc[i][j], 0, 0, 0);
        __syncthreads();
    }

    const int which = c0 >> 10;           // 0=Q 1=K 2=V (c0 < 3072, 128|1024)
    const int cc    = c0 & 1023;
    ushort* C = (which == 0) ? Q : ((which == 1) ? K : V);
    float* dptr = (which == 0) ? diagQ : ((which == 1) ? diagK : nullptr);

    #pragma unroll
    for (int i = 0; i < 4; ++i) {
        #pragma unroll
        for (int r = 0; r < 4; ++r) {
            const size_t grow = (size_t)(r0 + wm + i * 16 + quad * 4 + r);
            #pragma unroll
            for (int j = 0; j < 4; ++j)
                C[grow * DIM_ + cc + wn + j * 16 + col] = f2bu(acc[i][j][r]);
        }
    }
    if (dptr) {
        const int hglob = (cc + wn) >> 6;
        #pragma unroll
        for (int i = 0; i < 4; ++i) {
            #pragma unroll
            for (int r = 0; r < 4; ++r) {
                float s = 0.f;
                #pragma unroll
                for (int j = 0; j < 4; ++j) s += acc[i][j][r] * acc[i][j][r];
                s += __shfl_xor(s, 1); s += __shfl_xor(s, 2);
                s += __shfl_xor(s, 4); s += __shfl_xor(s, 8);
                if (col == 0)
                    dptr[(size_t)(r0 + wm + i * 16 + quad * 4 + r) * H_ + hglob] = DIAGC * s;
            }
        }
    }
}

// ---------------------------------------------------------------------------
// kctx v6: per-chunk partials WITH chunk-local max (kmax kernel absorbed).
// Phase A: 1 pass over chunk's K computing m_c (block max). Phase B: exp
// partials (no ratio/eps) + Vsum accumulation. Grid (NCH, 32).
// Outputs: ctxp[bh][c][m][e], kcsp[bh][c][m], vsump[bh][c][e], kmaxp[bh][c].
// ---------------------------------------------------------------------------
__launch_bounds__(256)
__global__ void kctx_mfma(const ushort* __restrict__ Kb, const ushort* __restrict__ Vb,
                          const ushort* __restrict__ projb,
                          const float* __restrict__ diagK,
                          float* __restrict__ ctxp, float* __restrict__ kcsp,
                          float* __restrict__ vsump, float* __restrict__ kmaxp)
{
    __shared__ ushort Pl[MP_ * 64];    // 36864 B (proj, resident, swizzled)
    __shared__ ushort Kp[MP_ * LKN];   // 23040 B (kp^T tile [m][n32])
    __shared__ ushort Vt[64 * LKN];    //  5120 B (V^T tile [e][n32])
    __shared__ float kred[2][MP_];     //  2304 B
    __shared__ float wmx[4];

    const int tid  = threadIdx.x;
    const int lane = tid & 63, wave = tid >> 6;
    const int col  = lane & 15, quad = lane >> 4;
    const int bh   = blockIdx.y, b = bh >> 4, h = bh & 15;
    const int n0   = blockIdx.x * (N_ / NCH);
    const int rowblk = wave >> 1;            // waves 0,1 -> n-rows 0-15; 2,3 -> 16-31
    const int t0 = (wave & 1) * 9;           // m-tiles: 0..8 / 9..17 (covers all 18)

    for (int i = tid; i < MP_ * 8; i += 256) {
        const int m = i >> 3, c = i & 7;
        *(uint4*)&Pl[m * 64 + ((c ^ (m & 7)) << 3)] = *(const uint4*)&projb[m * 64 + (c << 3)];
    }
    const int sw0 = (quad ^ (col & 7)) << 3;
    const int sw1 = ((quad | 4) ^ (col & 7)) << 3;
    __syncthreads();

    // ---- Phase A: chunk-local max over raw dd (K rows are L1/L2-warm after)
    float mx = -3.4e38f;
    {
        size_t arA = ((size_t)(b * N_ + n0 + rowblk * 16 + col)) * DIM_ + h * 64 + quad * 8;
        s8v pA0 = *(const s8v*)&Kb[arA];
        s8v pA1 = *(const s8v*)&Kb[arA + 32];
        for (int ks = 0; ks < KS_; ++ks) {
            const s8v a0 = pA0, a1 = pA1;
            if (ks + 1 < KS_) {
                arA += (size_t)32 * DIM_;
                pA0 = *(const s8v*)&Kb[arA];
                pA1 = *(const s8v*)&Kb[arA + 32];
            }
            for (int t = t0; t < t0 + 9; ++t) {
                const s8v bf0 = *(const s8v*)&Pl[(t * 16 + col) * 64 + sw0];
                const s8v bf1 = *(const s8v*)&Pl[(t * 16 + col) * 64 + sw1];
                f4v a = (f4v){0.f, 0.f, 0.f, 0.f};
                a = __builtin_amdgcn_mfma_f32_16x16x32_bf16(a0, bf0, a, 0, 0, 0);
                a = __builtin_amdgcn_mfma_f32_16x16x32_bf16(a1, bf1, a, 0, 0, 0);
                if (t * 16 + col < M_) {
                    #pragma unroll
                    for (int r = 0; r < 4; ++r) mx = fmaxf(mx, a[r]);
                }
            }
        }
    }
    #pragma unroll
    for (int o = 32; o > 0; o >>= 1) mx = fmaxf(mx, __shfl_xor(mx, o));
    if (lane == 0) wmx[wave] = mx;
    __syncthreads();
    const float mc = fmaxf(fmaxf(wmx[0], wmx[1]), fmaxf(wmx[2], wmx[3]));
    if (tid == 0) kmaxp[bh * NCH + blockIdx.x] = mc;

    // ---- Phase B: exp partials (unscaled) + ctx accumulation + Vsum
    const int nst = tid & 31, est = (tid >> 5) * 8;
    s8v vvP = *(const s8v*)&Vb[((size_t)(b * N_ + n0 + nst)) * DIM_ + h * 64 + est];
    const size_t arow0 = ((size_t)(b * N_ + n0 + rowblk * 16 + col)) * DIM_ + h * 64 + quad * 8;
    s8v afP0 = *(const s8v*)&Kb[arow0];
    s8v afP1 = *(const s8v*)&Kb[arow0 + 32];
    float dgrP[4];
    #pragma unroll
    for (int r = 0; r < 4; ++r)
        dgrP[r] = diagK[((size_t)(b * N_ + n0 + rowblk * 16 + quad * 4 + r)) * H_ + h];

    f4v facc[18];
    #pragma unroll
    for (int t = 0; t < 18; ++t) facc[t] = (f4v){0.f, 0.f, 0.f, 0.f};
    float kcsa[9] = {};
    float vsa[8] = {};

    for (int ks = 0; ks < KS_; ++ks) {
        const s8v vv = vvP, af0 = afP0, af1 = afP1;
        float dgr[4];
        #pragma unroll
        for (int r = 0; r < 4; ++r) dgr[r] = dgrP[r];

        // V^T stage from prefetched regs + Vsum accumulate (exact bf16->f32)
        #pragma unroll
        for (int j = 0; j < 8; ++j) {
            const ushort uv = ((const ushort*)&vv)[j];
            Vt[(est + j) * LKN + nst] = uv;
            vsa[j] += bu2f(uv);
        }

        for (int t = t0; t < t0 + 9; ++t) {
            const s8v bf0 = *(const s8v*)&Pl[(t * 16 + col) * 64 + sw0];
            const s8v bf1 = *(const s8v*)&Pl[(t * 16 + col) * 64 + sw1];
            f4v a = (f4v){0.f, 0.f, 0.f, 0.f};
            a = __builtin_amdgcn_mfma_f32_16x16x32_bf16(af0, bf0, a, 0, 0, 0);
            a = __builtin_amdgcn_mfma_f32_16x16x32_bf16(af1, bf1, a, 0, 0, 0);
            const int m = t * 16 + col;
            float kp[4];
            #pragma unroll
            for (int r = 0; r < 4; ++r) {
                float v = 0.f;
                if (m < M_) v = __expf(a[r] - dgr[r] - mc);
                kp[r] = v;
            }
            kcsa[t - t0] += kp[0] + kp[1] + kp[2] + kp[3];
            ushort4 pk;
            pk.x = f2bu(kp[0]); pk.y = f2bu(kp[1]); pk.z = f2bu(kp[2]); pk.w = f2bu(kp[3]);
            *(ushort4*)&Kp[m * LKN + rowblk * 16 + quad * 4] = pk;   // 4 consecutive n
        }

        // prefetch ks+1 (flies across both barriers + ctx MFMAs)
        if (ks + 1 < KS_) {
            const int nb1 = n0 + (ks + 1) * 32;
            vvP  = *(const s8v*)&Vb[((size_t)(b * N_ + nb1 + nst)) * DIM_ + h * 64 + est];
            const size_t arow1 = ((size_t)(b * N_ + nb1 + rowblk * 16 + col)) * DIM_ + h * 64 + quad * 8;
            afP0 = *(const s8v*)&Kb[arow1];
            afP1 = *(const s8v*)&Kb[arow1 + 32];
            #pragma unroll
            for (int r = 0; r < 4; ++r)
                dgrP[r] = diagK[((size_t)(b * N_ + nb1 + rowblk * 16 + quad * 4 + r)) * H_ + h];
        }
        __syncthreads();
        // out: wave owns e-tile = wave*16, all 18 m-tiles, k = 32 (this chunk)
        const s8v bfe = *(const s8v*)&Vt[(wave * 16 + col) * LKN + quad * 8];
        #pragma unroll
        for (int t = 0; t < 18; ++t) {
            const s8v am = *(const s8v*)&Kp[(t * 16 + col) * LKN + quad * 8];
            facc[t] = __builtin_amdgcn_mfma_f32_16x16x32_bf16(am, bfe, facc[t], 0, 0, 0);
        }
        __syncthreads();
    }

    // partial ctx: plain stores (D layout: m = t*16+quad*4+r, e = wave*16+col)
    const size_t pbase = ((size_t)bh * NCH + blockIdx.x) * (MP_ * 64);
    #pragma unroll
    for (int t = 0; t < 18; ++t) {
        #pragma unroll
        for (int r = 0; r < 4; ++r)
            ctxp[pbase + (size_t)(t * 16 + quad * 4 + r) * 64 + wave * 16 + col] = facc[t][r];
    }
    // Vsum partial: reduce over nst within each 32-lane half-wave
    #pragma unroll
    for (int j = 0; j < 8; ++j) {
        float s = vsa[j];
        s += __shfl_xor(s, 1);  s += __shfl_xor(s, 2);
        s += __shfl_xor(s, 4);  s += __shfl_xor(s, 8);
        s += __shfl_xor(s, 16);
        if ((lane & 31) == 0)
            vsump[((size_t)bh * NCH + blockIdx.x) * 64 + est + j] = s;
    }
    // partial kcs via LDS combine (waves 0/1 -> kred[0], 2/3 -> kred[1])
    for (int t = t0; t < t0 + 9; ++t) {
        float s = kcsa[t - t0];
        s += __shfl_xor(s, 16);
        s += __shfl_xor(s, 32);
        if (quad == 0) kred[rowblk][t * 16 + col] = s;
    }
    __syncthreads();
    for (int i = tid; i < MP_; i += 256)
        kcsp[((size_t)bh * NCH + blockIdx.x) * MP_ + i] = kred[0][i] + kred[1][i];
}

// ---------------------------------------------------------------------------
// Reduce partials with exact rescale: M = max_c m_c; scale_c = e^{m_c-M};
// ctxT = R*(Σ_c sc*S_c + E*Vsum); kcs = R*(Σ_c sc*s_c + E*N). Grid (8, 32).
// ---------------------------------------------------------------------------
__launch_bounds__(256)
__global__ void ctx_reduce(const float* __restrict__ ctxp, const float* __restrict__ kcsp,
                           const float* __restrict__ vsump, const float* __restrict__ kmaxp,
                           ushort* __restrict__ ctxT, float* __restrict__ kcs)
{
    __shared__ float scl[NCH];
    __shared__ float vsl[64];
    const int bh = blockIdx.y, tid = threadIdx.x;

    if (tid < NCH) {
        float M = -3.4e38f;
        #pragma unroll
        for (int c = 0; c < NCH; ++c) M = fmaxf(M, kmaxp[bh * NCH + c]);
        scl[tid] = __expf(kmaxp[bh * NCH + tid] - M);
    }
    if (tid >= 64 && tid < 128) {
        const int e = tid - 64;
        float s = 0.f;
        #pragma unroll
        for (int c = 0; c < NCH; ++c) s += vsump[((size_t)bh * NCH + c) * 64 + e];
        vsl[e] = s;
    }
    __syncthreads();

    const int base = blockIdx.x * (MP_ * 64 / 8);   // 2304
    const size_t cb = (size_t)bh * NCH * (MP_ * 64);
    #pragma unroll
    for (int u = 0; u < 9; ++u) {
        const int flat = base + u * 256 + tid;
        float s = 0.f;
        #pragma unroll
        for (int c = 0; c < NCH; ++c) s += scl[c] * ctxp[cb + (size_t)c * (MP_ * 64) + flat];
        const int m = flat >> 6, e = flat & 63;
        ctxT[((size_t)bh * 64 + e) * MP_ + m] = f2bu(RATIOC * (s + EPSC * vsl[e]));
    }
    if (blockIdx.x == 0) {
        for (int i = tid; i < MP_; i += 256) {
            float s = 0.f;
            #pragma unroll
            for (int c = 0; c < NCH; ++c) s += scl[c] * kcsp[((size_t)bh * NCH + c) * MP_ + i];
            kcs[(size_t)bh * MP_ + i] = RATIOC * (s + EPSC * (float)N_);
        }
    }
}

// ---------------------------------------------------------------------------
// Fused Q path, v5: early Qb/diag loads (above staging barrier); PV ctxT
// B-frags register-double-buffered with kk=0/1 issued before the transpose
// barriers (T14). Grid (64, 32).
// ---------------------------------------------------------------------------
__launch_bounds__(256)
__global__ void qdashout(const ushort* __restrict__ Qb, const ushort* __restrict__ projb,
                         const float* __restrict__ diagQ, const float* __restrict__ kcs,
                         const ushort* __restrict__ ctxT, ushort* __restrict__ Ab)
{
    __shared__ ushort SB[64 * LSB];   // 37888 B: proj swizzled [m][64] (18432) then qp [n][LSB]
    __shared__ float kcl[MP_];
    __shared__ float dinv[64];

    const int tid  = threadIdx.x;
    const int lane = tid & 63, wave = tid >> 6;
    const int col  = lane & 15, quad = lane >> 4;
    const int bh   = blockIdx.y, b = bh >> 4, h = bh & 15;
    const int n0   = blockIdx.x * 64;

    // early: issue Qb row loads + diagQ before the staging barrier
    const size_t arow = ((size_t)(b * N_ + n0 + wave * 16 + col)) * DIM_ + h * 64 + quad * 8;
    const s8v af0 = *(const s8v*)&Qb[arow];
    const s8v af1 = *(const s8v*)&Qb[arow + 32];
    float dgr[4];
    #pragma unroll
    for (int r = 0; r < 4; ++r)
        dgr[r] = diagQ[((size_t)(b * N_ + n0 + wave * 16 + quad * 4 + r)) * H_ + h];

    // proj -> LDS, 16B-block swizzle kb^(m&7) to spread the stride-128B banks
    for (int i = tid; i < MP_ * 8; i += 256) {
        const int m = i >> 3, c = i & 7;
        *(uint4*)&SB[m * 64 + ((c ^ (m & 7)) << 3)] = *(const uint4*)&projb[m * 64 + (c << 3)];
    }
    for (int i = tid; i < MP_; i += 256) kcl[i] = kcs[(size_t)bh * MP_ + i];
    __syncthreads();

    // dash: C rows n = wave*16 + quad*4 + r, cols m = t*16 + col
    const int sw0 = (quad ^ (col & 7)) << 3;          // m&7 == col&7 for rows t*16+col
    const int sw1 = ((quad | 4) ^ (col & 7)) << 3;

    f4v acc[17];
    #pragma unroll
    for (int t = 0; t < 17; ++t) {
        const s8v bf0 = *(const s8v*)&SB[(t * 16 + col) * 64 + sw0];
        const s8v bf1 = *(const s8v*)&SB[(t * 16 + col) * 64 + sw1];
        f4v a = (f4v){0.f, 0.f, 0.f, 0.f};
        a = __builtin_amdgcn_mfma_f32_16x16x32_bf16(af0, bf0, a, 0, 0, 0);
        a = __builtin_amdgcn_mfma_f32_16x16x32_bf16(af1, bf1, a, 0, 0, 0);
        acc[t] = a;
    }

    float rmx[4];
    #pragma unroll
    for (int r = 0; r < 4; ++r) {
        float mx = -3.4e38f;
        #pragma unroll
        for (int t = 0; t < 16; ++t) mx = fmaxf(mx, acc[t][r]);
        if (col < 10) mx = fmaxf(mx, acc[16][r]);
        mx = fmaxf(mx, __shfl_xor(mx, 1));
        mx = fmaxf(mx, __shfl_xor(mx, 2));
        mx = fmaxf(mx, __shfl_xor(mx, 4));
        mx = fmaxf(mx, __shfl_xor(mx, 8));
        rmx[r] = mx;
    }

    float den[4] = {0.f, 0.f, 0.f, 0.f};
    #pragma unroll
    for (int t = 0; t < 17; ++t) {
        const int m = t * 16 + col;
        const float kc = kcl[m];
        #pragma unroll
        for (int r = 0; r < 4; ++r) {
            float v = 0.f;
            if (m < M_)
                v = RATIOC * (__expf(acc[t][r] - dgr[r] - rmx[r]) + EPSC);
            acc[t][r] = v;
            den[r] += v * kc;
        }
    }

    // T14 issue-early: PV B-frags for kk=0 fly across the 2 barriers below
    const ushort* ct = ctxT + (size_t)bh * 64 * MP_;
    s8v bfA[4], bfB[4];
    #pragma unroll
    for (int j = 0; j < 4; ++j)
        bfA[j] = *(const s8v*)&ct[(size_t)(j * 16 + col) * MP_ + quad * 8];

    __syncthreads();   // all proj reads done before SB is overwritten with qp

    // qp -> SB in A-layout-ready form: SB[n][m] stride LSB, zero m in [272,288)
    #pragma unroll
    for (int r = 0; r < 4; ++r) {
        const int rb = (wave * 16 + quad * 4 + r) * LSB;
        #pragma unroll
        for (int t = 0; t < 17; ++t)
            SB[rb + t * 16 + col] = f2bu(acc[t][r]);
        if (col < 8) *(uint*)&SB[rb + 272 + col * 2] = 0u;
    }
    #pragma unroll
    for (int r = 0; r < 4; ++r) {
        float d = den[r];
        d += __shfl_xor(d, 1); d += __shfl_xor(d, 2);
        d += __shfl_xor(d, 4); d += __shfl_xor(d, 8);
        if (col == 0)
            dinv[wave * 16 + quad * 4 + r] = 1.0f / fmaxf(d, 1e-30f);
    }
    __syncthreads();

    // PV: A rows n = wave*16+col (from SB), B rows e = j*16+col from GLOBAL
    // ctxT, register-double-buffered (all indices compile-time).
    f4v acc2[4];
    #pragma unroll
    for (int j = 0; j < 4; ++j) acc2[j] = (f4v){0.f, 0.f, 0.f, 0.f};
    #pragma unroll
    for (int kp = 0; kp < 4; ++kp) {
        const int k0 = 2 * kp, k1 = 2 * kp + 1, k2 = 2 * kp + 2;
        #pragma unroll
        for (int j = 0; j < 4; ++j)
            bfB[j] = *(const s8v*)&ct[(size_t)(j * 16 + col) * MP_ + k1 * 32 + quad * 8];
        const s8v afrA = *(const s8v*)&SB[(wave * 16 + col) * LSB + k0 * 32 + quad * 8];
        #pragma unroll
        for (int j = 0; j < 4; ++j)
            acc2[j] = __builtin_amdgcn_mfma_f32_16x16x32_bf16(afrA, bfA[j], acc2[j], 0, 0, 0);
        #pragma unroll
        for (int j = 0; j < 4; ++j)
            bfA[j] = *(const s8v*)&ct[(size_t)(j * 16 + col) * MP_ + k2 * 32 + quad * 8];
        const s8v afrB = *(const s8v*)&SB[(wave * 16 + col) * LSB + k1 * 32 + quad * 8];
        #pragma unroll
        for (int j = 0; j < 4; ++j)
            acc2[j] = __builtin_amdgcn_mfma_f32_16x16x32_bf16(afrB, bfB[j], acc2[j], 0, 0, 0);
    }
    {   // kk = 8 tail (bfA holds it)
        const s8v afrT = *(const s8v*)&SB[(wave * 16 + col) * LSB + 8 * 32 + quad * 8];
        #pragma unroll
        for (int j = 0; j < 4; ++j)
            acc2[j] = __builtin_amdgcn_mfma_f32_16x16x32_bf16(afrT, bfA[j], acc2[j], 0, 0, 0);
    }
    #pragma unroll
    for (int j = 0; j < 4; ++j) {
        #pragma unroll
        for (int r = 0; r < 4; ++r) {
            const int n = wave * 16 + quad * 4 + r;
            Ab[((size_t)(b * N_ + n0 + n)) * DIM_ + h * 64 + j * 16 + col] =
                f2bu(acc2[j][r] * dinv[n]);
        }
    }
}

// ---------------------------------------------------------------------------
extern "C" void kernel_launch(void* const* d_in, const int* in_sizes, int n_in,
                              void* d_out, int out_size, void* d_ws, size_t ws_size,
                              hipStream_t stream)
{
    const float* x    = (const float*)d_in[0];
    const float* Wq   = (const float*)d_in[1];
    const float* Wk   = (const float*)d_in[2];
    const float* Wv   = (const float*)d_in[3];
    const float* Wo   = (const float*)d_in[4];
    const float* bo   = (const float*)d_in[5];
    const float* proj = (const float*)d_in[6];

    char* ws = (char*)d_ws;
    size_t o = 0;
    ushort* xb    = (ushort*)(ws + o); o += (size_t)RT_ * DIM_ * 2;
    ushort* Wqb   = (ushort*)(ws + o); o += (size_t)DIM_ * DIM_ * 2;   // Wq;Wk;Wv contiguous
    ushort* Wkb   = (ushort*)(ws + o); o += (size_t)DIM_ * DIM_ * 2;
    ushort* Wvb   = (ushort*)(ws + o); o += (size_t)DIM_ * DIM_ * 2;
    ushort* Wob   = (ushort*)(ws + o); o += (size_t)DIM_ * DIM_ * 2;
    ushort* projb = (ushort*)(ws + o); o += (size_t)MP_ * 64 * 2;
    ushort* Qb    = (ushort*)(ws + o); o += (size_t)RT_ * DIM_ * 2;
    ushort* Kb    = (ushort*)(ws + o); o += (size_t)RT_ * DIM_ * 2;
    ushort* Vb    = (ushort*)(ws + o); o += (size_t)RT_ * DIM_ * 2;
    ushort* Ab    = (ushort*)(ws + o); o += (size_t)RT_ * DIM_ * 2;
    float*    ctxp  = (float*)(ws + o);    o += (size_t)BH_ * NCH * MP_ * 64 * 4;  // 37.75 MB
    float*    kcsp  = (float*)(ws + o);    o += (size_t)BH_ * NCH * MP_ * 4;
    float*    kcs   = (float*)(ws + o);    o += (size_t)BH_ * MP_ * 4;
    float*    vsump = (float*)(ws + o);    o += (size_t)BH_ * NCH * 64 * 4;
    float*    kmaxp = (float*)(ws + o);    o += (size_t)BH_ * NCH * 4;
    float*    diagQ = (float*)(ws + o);    o += (size_t)RT_ * H_ * 4;
    float*    diagK = (float*)(ws + o);    o += (size_t)RT_ * H_ * 4;
    ushort*   ctxT  = (ushort*)(ws + o);   o += (size_t)BH_ * 64 * MP_ * 2;

    cast_x<<<dim3(RT_ * DIM_ / 2048), 256, 0, stream>>>(x, xb);
    cast_w<<<dim3(DIM_ * DIM_ / 2048, 4), 256, 0, stream>>>(Wq, Wk, Wv, Wo, Wqb, Wkb, Wvb, Wob);
    cast_proj<<<dim3(MP_ * 64 / 256), 256, 0, stream>>>(proj, projb);

    // fused QKV: B = [Wq;Wk;Wv] = 3072x1024 (contiguous), grid 24x64
    gemm128_qkv<<<dim3(24, RT_ / 128), 256, 0, stream>>>(xb, Wqb, Qb, Kb, Vb, diagQ, diagK);

    kctx_mfma<<<dim3(NCH, BH_), 256, 0, stream>>>(Kb, Vb, projb, diagK, ctxp, kcsp, vsump, kmaxp);
    ctx_reduce<<<dim3(8, BH_), 256, 0, stream>>>(ctxp, kcsp, vsump, kmaxp, ctxT, kcs);
    qdashout<<<dim3(N_ / 64, BH_), 256, 0, stream>>>(Qb, projb, diagQ, kcs, ctxT, Ab);

    gemm128<false, true, float><<<dim3(DIM_ / 128, RT_ / 128), 256, 0, stream>>>(Ab, Wob, bo, (float*)d_out, nullptr);
}